// Round 1
// baseline (834.564 us; speedup 1.0000x reference)
//
#include <hip/hip_runtime.h>

#define NEGV (-1e30f)

// Problem constants (from setup_inputs): B=4, NP=5000
static constexpr int E0 = 160000;   // edges (fixed array size at every level)
static constexpr int NL0 = 20000;   // nodes level 0
static constexpr int NL1 = 6912;    // 4 * 12^3   (voxel 20)
static constexpr int NL2 = 2048;    // 4 * 8^3    (voxel 30)
static constexpr int NL3 = 500;     // 4 * 5^3    (voxel 50)

// ---------- helpers ----------
__device__ __forceinline__ unsigned f2ord(float f) {
  unsigned u = __float_as_uint(f);
  return (u & 0x80000000u) ? ~u : (u | 0x80000000u);
}
__device__ __forceinline__ float ord2f(unsigned u) {
  unsigned v = (u & 0x80000000u) ? (u & 0x7fffffffu) : ~u;
  return __uint_as_float(v);
}
__device__ __forceinline__ float eluf(float x) { return x > 0.f ? x : expm1f(x); }
__device__ __forceinline__ void basis8(float u0, float u1, float u2, float* w) {
  float a0 = 1.f - u0, a1 = 1.f - u1, a2 = 1.f - u2;
  w[0] = a0*a1*a2; w[1] = a0*a1*u2; w[2] = a0*u1*a2; w[3] = a0*u1*u2;
  w[4] = u0*a1*a2; w[5] = u0*a1*u2; w[6] = u0*u1*a2; w[7] = u0*u1*u2;
}

// ---------- edge convert (int32 per harness doc) ----------
__global__ void k_convert(const int* __restrict__ ei, int* __restrict__ s,
                          int* __restrict__ d, int E) {
  int e = blockIdx.x * blockDim.x + threadIdx.x;
  if (e < E) { s[e] = ei[e]; d[e] = ei[E + e]; }
}

// ---------- global max |rel| over valid edges ----------
__global__ void k_absmax(const float* __restrict__ pos, const int* __restrict__ src,
                         const int* __restrict__ dst, const int* __restrict__ ecnt,
                         int ecap, float* __restrict__ m) {
  int n = ecnt ? *ecnt : ecap;
  float v = 0.f;
  for (int e = blockIdx.x * blockDim.x + threadIdx.x; e < n;
       e += gridDim.x * blockDim.x) {
    int s = src[e], d = dst[e];
    #pragma unroll
    for (int c = 0; c < 3; c++)
      v = fmaxf(v, fabsf(pos[s*3+c] - pos[d*3+c]));
  }
  for (int off = 32; off; off >>= 1) v = fmaxf(v, __shfl_down(v, off, 64));
  __shared__ float red[4];
  int lane = threadIdx.x & 63, wv = threadIdx.x >> 6;
  if (lane == 0) red[wv] = v;
  __syncthreads();
  if (threadIdx.x == 0) {
    float mm = fmaxf(fmaxf(red[0], red[1]), fmaxf(red[2], red[3]));
    atomicMax((unsigned*)m, __float_as_uint(mm));  // non-negative floats: uint-ordered
  }
}

// ---------- tiled fp32 GEMM: C[z] = A @ B[z]  (64x64 tile, 4x4 micro) ----------
__global__ __launch_bounds__(256)
void k_gemm(const float* __restrict__ A, const float* __restrict__ Bg,
            float* __restrict__ Cg, int M, int N, int K,
            int lda, int ldb, int ldc, long bz, long cz) {
  const float* B = Bg + (long)blockIdx.z * bz;
  float* C = Cg + (long)blockIdx.z * cz;
  __shared__ __align__(16) float As[16][68];
  __shared__ __align__(16) float Bs[16][68];
  int m0 = blockIdx.y * 64, n0 = blockIdx.x * 64;
  int t = threadIdx.x;
  int ti = t >> 4, tj = t & 15;
  float acc[4][4] = {};
  for (int kt = 0; kt < K; kt += 16) {
    #pragma unroll
    for (int r = 0; r < 4; r++) {
      int q = t + r * 256;
      int k = q & 15, mm = q >> 4;
      int gm = m0 + mm, gk = kt + k;
      As[k][mm] = (gm < M && gk < K) ? A[(long)gm * lda + gk] : 0.f;
    }
    #pragma unroll
    for (int r = 0; r < 4; r++) {
      int q = t + r * 256;
      int n = q & 63, k = q >> 6;
      int gk = kt + k, gn = n0 + n;
      Bs[k][n] = (gk < K && gn < N) ? B[(long)gk * ldb + gn] : 0.f;
    }
    __syncthreads();
    #pragma unroll
    for (int kk = 0; kk < 16; kk++) {
      float4 a = *(const float4*)&As[kk][ti * 4];
      float4 b = *(const float4*)&Bs[kk][tj * 4];
      float av[4] = {a.x, a.y, a.z, a.w}, bv[4] = {b.x, b.y, b.z, b.w};
      #pragma unroll
      for (int i = 0; i < 4; i++)
        #pragma unroll
        for (int j = 0; j < 4; j++) acc[i][j] += av[i] * bv[j];
    }
    __syncthreads();
  }
  #pragma unroll
  for (int i = 0; i < 4; i++) {
    int gm = m0 + ti * 4 + i;
    if (gm >= M) continue;
    #pragma unroll
    for (int j = 0; j < 4; j++) {
      int gn = n0 + tj * 4 + j;
      if (gn < N) C[(long)gm * ldc + gn] = acc[i][j];
    }
  }
}

// ---------- layer-1 message (Ci=1, Co=64): msg = x[s] * sum_k b_k W1[k,0,:] ----------
__global__ void k_msg1(const float* __restrict__ pos, const int* __restrict__ src,
                       const int* __restrict__ dst, const float* __restrict__ m,
                       const float* __restrict__ x, const float* __restrict__ W1,
                       float* __restrict__ agg, float* __restrict__ deg) {
  float inv = 0.5f / fmaxf(m[0], 1e-9f);
  long tot = (long)E0 * 16;
  long stride = (long)gridDim.x * blockDim.x;
  for (long idx = (long)blockIdx.x * blockDim.x + threadIdx.x; idx < tot; idx += stride) {
    int e = (int)(idx >> 4), og = (int)(idx & 15);
    int s = src[e], d = dst[e];
    float u0 = (pos[s*3+0] - pos[d*3+0]) * inv + 0.5f;
    float u1 = (pos[s*3+1] - pos[d*3+1]) * inv + 0.5f;
    float u2 = (pos[s*3+2] - pos[d*3+2]) * inv + 0.5f;
    float w[8]; basis8(u0, u1, u2, w);
    float xv = x[s];
    float s0 = 0, s1 = 0, s2 = 0, s3 = 0;
    #pragma unroll
    for (int k = 0; k < 8; k++) {
      const float* Wk = W1 + k * 64 + og;
      s0 += w[k] * Wk[0];  s1 += w[k] * Wk[16];
      s2 += w[k] * Wk[32]; s3 += w[k] * Wk[48];
    }
    float* ag = agg + (long)d * 64 + og;
    atomicAdd(ag + 0,  xv * s0); atomicAdd(ag + 16, xv * s1);
    atomicAdd(ag + 32, xv * s2); atomicAdd(ag + 48, xv * s3);
    if (og == 0) atomicAdd(&deg[d], 1.f);
  }
}

// ---------- generic message: msg_o = sum_k b_k xk[s,k,o] ----------
__global__ void k_msg(const float* __restrict__ pos, const int* __restrict__ src,
                      const int* __restrict__ dst, const int* __restrict__ ecnt,
                      int ecap, const float* __restrict__ m, const float* __restrict__ xk,
                      float* __restrict__ agg, float* __restrict__ deg,
                      int Co, int qsh) {
  int ne = ecnt ? *ecnt : ecap;
  int Q = Co >> 2;
  float inv = 0.5f / fmaxf(m[0], 1e-9f);
  long tot = (long)ne << qsh;
  long stride = (long)gridDim.x * blockDim.x;
  for (long idx = (long)blockIdx.x * blockDim.x + threadIdx.x; idx < tot; idx += stride) {
    int e = (int)(idx >> qsh), og = (int)(idx & (Q - 1));
    int s = src[e], d = dst[e];
    float u0 = (pos[s*3+0] - pos[d*3+0]) * inv + 0.5f;
    float u1 = (pos[s*3+1] - pos[d*3+1]) * inv + 0.5f;
    float u2 = (pos[s*3+2] - pos[d*3+2]) * inv + 0.5f;
    float w[8]; basis8(u0, u1, u2, w);
    const float* xs = xk + (long)s * (Co * 8) + og;
    float m0 = 0, m1 = 0, m2 = 0, m3 = 0;
    #pragma unroll
    for (int k = 0; k < 8; k++) {
      float wk = w[k];
      const float* p = xs + k * Co;
      m0 += wk * p[0];     m1 += wk * p[Q];
      m2 += wk * p[2 * Q]; m3 += wk * p[3 * Q];
    }
    float* ag = agg + (long)d * Co + og;
    atomicAdd(ag, m0);         atomicAdd(ag + Q, m1);
    atomicAdd(ag + 2 * Q, m2); atomicAdd(ag + 3 * Q, m3);
    if (og == 0) atomicAdd(&deg[d], 1.f);
  }
}

// ---------- finish conv: out = elu(agg/max(deg,1) + xr + b) ----------
__global__ void k_finish(const float* __restrict__ agg, const float* __restrict__ deg,
                         const float* __restrict__ xr, const float* __restrict__ b,
                         float* __restrict__ out, int N, int Co) {
  long idx = (long)blockIdx.x * blockDim.x + threadIdx.x;
  if (idx >= (long)N * Co) return;
  int n = (int)(idx / Co), o = (int)(idx % Co);
  out[idx] = eluf(agg[idx] / fmaxf(deg[n], 1.f) + xr[idx] + b[o]);
}

// ---------- voxel id + count + pos sums ----------
__global__ void k_nid(const float* __restrict__ pos, const unsigned char* __restrict__ valid,
                      int Nf, int div, float vs, int G, int NC,
                      int* __restrict__ nid, float* __restrict__ cnt,
                      float* __restrict__ possum) {
  int v = blockIdx.x * blockDim.x + threadIdx.x;
  if (v >= Nf) return;
  float p0 = pos[v*3+0], p1 = pos[v*3+1], p2 = pos[v*3+2];
  int c0 = (int)floorf(p0 / vs); c0 = c0 < 0 ? 0 : (c0 > G-1 ? G-1 : c0);
  int c1 = (int)floorf(p1 / vs); c1 = c1 < 0 ? 0 : (c1 > G-1 ? G-1 : c1);
  int c2 = (int)floorf(p2 / vs); c2 = c2 < 0 ? 0 : (c2 > G-1 ? G-1 : c2);
  int id = (v / div) * NC + (c0 * G + c1) * G + c2;
  nid[v] = id;
  if (valid && !valid[v]) return;
  atomicAdd(&cnt[id], 1.f);
  atomicAdd(&possum[id*3+0], p0);
  atomicAdd(&possum[id*3+1], p1);
  atomicAdd(&possum[id*3+2], p2);
}

__global__ void k_pool_x(const float* __restrict__ x, const unsigned char* __restrict__ valid,
                         const int* __restrict__ nid, unsigned* __restrict__ pord,
                         int Nf, int Cf) {
  long idx = (long)blockIdx.x * blockDim.x + threadIdx.x;
  if (idx >= (long)Nf * Cf) return;
  int v = (int)(idx / Cf), o = (int)(idx % Cf);
  if (valid && !valid[v]) return;
  atomicMax(&pord[(long)nid[v] * Cf + o], f2ord(x[idx]));
}

__global__ void k_pool_fin(const unsigned* __restrict__ pord, const float* __restrict__ cnt,
                           const float* __restrict__ possum, float* __restrict__ xp,
                           float* __restrict__ posp, unsigned char* __restrict__ validp,
                           int Nn, int Cf) {
  long idx = (long)blockIdx.x * blockDim.x + threadIdx.x;
  if (idx >= (long)Nn * Cf) return;
  int n = (int)(idx / Cf), o = (int)(idx % Cf);
  float c = cnt[n];
  xp[idx] = (c > 0.f) ? ord2f(pord[idx]) : 0.f;
  if (o == 0) {
    validp[n] = (c > 0.f) ? 1 : 0;
    float ic = 1.f / fmaxf(c, 1.f);
    posp[n*3+0] = possum[n*3+0] * ic;
    posp[n*3+1] = possum[n*3+1] * ic;
    posp[n*3+2] = possum[n*3+2] * ic;
  }
}

// ---------- edge coarsening with bitmap dedup + compaction ----------
__global__ void k_pool_edges(const int* __restrict__ srcf, const int* __restrict__ dstf,
                             const int* __restrict__ ecntf, int ecap,
                             const int* __restrict__ nid, int Nn,
                             unsigned* __restrict__ bitmap,
                             int* __restrict__ srcc, int* __restrict__ dstc,
                             int* __restrict__ ecntc) {
  int n = ecntf ? *ecntf : ecap;
  for (int e = blockIdx.x * blockDim.x + threadIdx.x; e < n;
       e += gridDim.x * blockDim.x) {
    int s2 = nid[srcf[e]], d2 = nid[dstf[e]];
    if (s2 == d2) continue;
    unsigned key = (unsigned)s2 * (unsigned)Nn + (unsigned)d2;
    unsigned bit = 1u << (key & 31);
    unsigned old = atomicOr(&bitmap[key >> 5], bit);
    if (!(old & bit)) {
      int p = atomicAdd(ecntc, 1);
      srcc[p] = s2; dstc[p] = d2;
    }
  }
}

// ---------- final pooling + FC ----------
__global__ void k_fill_neg(unsigned* __restrict__ p, int n) {
  int i = blockIdx.x * blockDim.x + threadIdx.x;
  if (i < n) p[i] = f2ord(NEGV);
}

__global__ void k_final_pool(const float* __restrict__ x, const float* __restrict__ pos,
                             const unsigned char* __restrict__ valid,
                             unsigned* __restrict__ xg_ord) {
  long idx = (long)blockIdx.x * blockDim.x + threadIdx.x;
  if (idx >= (long)NL3 * 512) return;
  int v = (int)(idx >> 9), o = (int)(idx & 511);
  if (!valid[v]) return;
  const float vs = 80.f; const int G = 3;
  float p0 = pos[v*3+0], p1 = pos[v*3+1], p2 = pos[v*3+2];
  int c0 = (int)floorf(p0 / vs); c0 = c0 < 0 ? 0 : (c0 > G-1 ? G-1 : c0);
  int c1 = (int)floorf(p1 / vs); c1 = c1 < 0 ? 0 : (c1 > G-1 ? G-1 : c1);
  int c2 = (int)floorf(p2 / vs); c2 = c2 < 0 ? 0 : (c2 > G-1 ? G-1 : c2);
  int cell = (c0 * G + c1) * G + c2;
  int cluster = (v / 125) * 64 + cell;
  atomicMax(&xg_ord[cluster * 512 + o], f2ord(x[idx]));
}

__global__ void k_xg_fin(const unsigned* __restrict__ xg_ord, float* __restrict__ xg) {
  int i = blockIdx.x * blockDim.x + threadIdx.x;
  if (i >= 4 * 64 * 512) return;
  float f = ord2f(xg_ord[i]);
  xg[i] = (f <= NEGV * 0.5f) ? 0.f : f;
}

// FC1: only cells 0..26 can be nonzero -> skip 37/64 of the 134MB weight.
__global__ __launch_bounds__(128)
void k_fc1(const float* __restrict__ xg, const float* __restrict__ w,
           float* __restrict__ h) {
  int cellhalf = blockIdx.x >> 3, jb = blockIdx.x & 7;
  int cell = cellhalf >> 1, half = cellhalf & 1;
  int j = jb * 128 + threadIdx.x;
  __shared__ float xs[4][256];
  for (int q = threadIdx.x; q < 1024; q += 128) {
    int b = q >> 8, ci = q & 255;
    xs[b][ci] = xg[((b * 64 + cell) << 9) + half * 256 + ci];
  }
  __syncthreads();
  float a0 = 0, a1 = 0, a2 = 0, a3 = 0;
  int cbase = cell * 512 + half * 256;
  for (int ci = 0; ci < 256; ci++) {
    float ww = w[(long)(cbase + ci) * 1024 + j];
    a0 += xs[0][ci] * ww; a1 += xs[1][ci] * ww;
    a2 += xs[2][ci] * ww; a3 += xs[3][ci] * ww;
  }
  atomicAdd(&h[j], a0);        atomicAdd(&h[1024 + j], a1);
  atomicAdd(&h[2048 + j], a2); atomicAdd(&h[3072 + j], a3);
}

__global__ void k_fc1fin(float* __restrict__ h, const float* __restrict__ b) {
  int i = blockIdx.x * blockDim.x + threadIdx.x;
  if (i < 4096) h[i] = eluf(h[i] + b[i & 1023]);
}

__global__ void k_fc2(const float* __restrict__ h, const float* __restrict__ w,
                      const float* __restrict__ b, float* __restrict__ out) {
  int bb = blockIdx.x, t = threadIdx.x;
  float a = 0;
  for (int j = t; j < 1024; j += 256) a += h[bb * 1024 + j] * w[j];
  for (int off = 32; off; off >>= 1) a += __shfl_down(a, off, 64);
  __shared__ float red[4];
  int lane = t & 63, wv = t >> 6;
  if (lane == 0) red[wv] = a;
  __syncthreads();
  if (t == 0) out[bb] = eluf(red[0] + red[1] + red[2] + red[3] + b[0]);
}

// =======================================================================
extern "C" void kernel_launch(void* const* d_in, const int* in_sizes, int n_in,
                              void* d_out, int out_size, void* d_ws, size_t ws_size,
                              hipStream_t stream) {
  const float* x0   = (const float*)d_in[0];
  const float* pos0 = (const float*)d_in[1];
  const int*   ei   = (const int*)d_in[2];
  const float* W1 = (const float*)d_in[4],  *Wr1 = (const float*)d_in[5],  *b1 = (const float*)d_in[6];
  const float* W2 = (const float*)d_in[7],  *Wr2 = (const float*)d_in[8],  *b2 = (const float*)d_in[9];
  const float* W3 = (const float*)d_in[10], *Wr3 = (const float*)d_in[11], *b3 = (const float*)d_in[12];
  const float* W4 = (const float*)d_in[13], *Wr4 = (const float*)d_in[14], *b4 = (const float*)d_in[15];
  const float* fw1 = (const float*)d_in[16], *fb1 = (const float*)d_in[17];
  const float* fw2 = (const float*)d_in[18], *fb2 = (const float*)d_in[19];
  float* out = (float*)d_out;

  // ---- workspace layout (~68 MB) ----
  char* ws = (char*)d_ws;
  size_t off = 0;
  auto alloc = [&](size_t bytes) -> void* {
    off = (off + 255) & ~(size_t)255;
    void* p = ws + off; off += bytes; return p;
  };
  int* src0 = (int*)alloc(E0 * 4); int* dst0 = (int*)alloc(E0 * 4);
  int* src1 = (int*)alloc(E0 * 4); int* dst1 = (int*)alloc(E0 * 4);
  int* src2 = (int*)alloc(E0 * 4); int* dst2 = (int*)alloc(E0 * 4);
  int* src3 = (int*)alloc(E0 * 4); int* dst3 = (int*)alloc(E0 * 4);
  float* x1  = (float*)alloc((size_t)NL0 * 64 * 4);
  float* x1p = (float*)alloc((size_t)NL1 * 64 * 4);
  float* x2  = (float*)alloc((size_t)NL1 * 128 * 4);
  float* x2p = (float*)alloc((size_t)NL2 * 128 * 4);
  float* x3  = (float*)alloc((size_t)NL2 * 256 * 4);
  float* x3p = (float*)alloc((size_t)NL3 * 256 * 4);
  float* x4  = (float*)alloc((size_t)NL3 * 512 * 4);
  float* pos1 = (float*)alloc(NL1 * 12);
  float* pos2 = (float*)alloc(NL2 * 12);
  float* pos3 = (float*)alloc(NL3 * 12);
  unsigned char* val1 = (unsigned char*)alloc(NL1);
  unsigned char* val2 = (unsigned char*)alloc(NL2);
  unsigned char* val3 = (unsigned char*)alloc(NL3);
  float* cnt    = (float*)alloc(NL1 * 4);
  float* possum = (float*)alloc(NL1 * 12);
  unsigned* pord = (unsigned*)alloc((size_t)NL1 * 64 * 4);   // also reused as xg_ord
  float* xk  = (float*)alloc((size_t)NL1 * 8 * 128 * 4);     // biggest xk = 28.3MB
  float* xr  = (float*)alloc((size_t)NL0 * 64 * 4);
  float* agg = (float*)alloc((size_t)NL0 * 64 * 4);
  float* deg = (float*)alloc(NL0 * 4);
  int* nid   = (int*)alloc(NL0 * 4);
  size_t bmwords = ((size_t)NL1 * NL1 + 31) / 32;
  unsigned* bitmap = (unsigned*)alloc(bmwords * 4);
  float* mbuf = (float*)alloc(16);
  int* ecnt   = (int*)alloc(16);
  float* xg   = (float*)alloc(4 * 64 * 512 * 4);
  float* h    = (float*)alloc(4096 * 4);
  (void)ws_size; (void)in_sizes; (void)n_in; (void)out_size;

  auto cdiv = [](long a, long b) { return (int)((a + b - 1) / b); };

  hipMemsetAsync(mbuf, 0, 16, stream);
  hipMemsetAsync(ecnt, 0, 16, stream);
  k_convert<<<cdiv(E0, 256), 256, 0, stream>>>(ei, src0, dst0, E0);

  // ===== Layer 1 (1 -> 64), level-0 graph =====
  k_absmax<<<512, 256, 0, stream>>>(pos0, src0, dst0, nullptr, E0, mbuf + 0);
  hipMemsetAsync(agg, 0, (size_t)NL0 * 64 * 4, stream);
  hipMemsetAsync(deg, 0, NL0 * 4, stream);
  k_msg1<<<2048, 256, 0, stream>>>(pos0, src0, dst0, mbuf + 0, x0, W1, agg, deg);
  k_gemm<<<dim3(1, cdiv(NL0, 64), 1), 256, 0, stream>>>(x0, Wr1, xr, NL0, 64, 1, 1, 64, 64, 0, 0);
  k_finish<<<cdiv((long)NL0 * 64, 256), 256, 0, stream>>>(agg, deg, xr, b1, x1, NL0, 64);

  // ===== Pool 1 (vs=20, G=12, NC=1728) =====
  hipMemsetAsync(cnt, 0, NL1 * 4, stream);
  hipMemsetAsync(possum, 0, NL1 * 12, stream);
  hipMemsetAsync(pord, 0, (size_t)NL1 * 64 * 4, stream);
  hipMemsetAsync(bitmap, 0, bmwords * 4, stream);
  k_nid<<<cdiv(NL0, 256), 256, 0, stream>>>(pos0, nullptr, NL0, 5000, 20.f, 12, 1728, nid, cnt, possum);
  k_pool_x<<<cdiv((long)NL0 * 64, 256), 256, 0, stream>>>(x1, nullptr, nid, pord, NL0, 64);
  k_pool_fin<<<cdiv((long)NL1 * 64, 256), 256, 0, stream>>>(pord, cnt, possum, x1p, pos1, val1, NL1, 64);
  k_pool_edges<<<512, 256, 0, stream>>>(src0, dst0, nullptr, E0, nid, NL1, bitmap, src1, dst1, ecnt + 0);

  // ===== Layer 2 (64 -> 128) =====
  k_absmax<<<512, 256, 0, stream>>>(pos1, src1, dst1, ecnt + 0, E0, mbuf + 1);
  k_gemm<<<dim3(2, cdiv(NL1, 64), 8), 256, 0, stream>>>(x1p, W2, xk, NL1, 128, 64, 64, 128, 1024, 64L * 128, 128);
  k_gemm<<<dim3(2, cdiv(NL1, 64), 1), 256, 0, stream>>>(x1p, Wr2, xr, NL1, 128, 64, 64, 128, 128, 0, 0);
  hipMemsetAsync(agg, 0, (size_t)NL1 * 128 * 4, stream);
  hipMemsetAsync(deg, 0, NL1 * 4, stream);
  k_msg<<<2048, 256, 0, stream>>>(pos1, src1, dst1, ecnt + 0, E0, mbuf + 1, xk, agg, deg, 128, 5);
  k_finish<<<cdiv((long)NL1 * 128, 256), 256, 0, stream>>>(agg, deg, xr, b2, x2, NL1, 128);

  // ===== Pool 2 (vs=30, G=8, NC=512) =====
  hipMemsetAsync(cnt, 0, NL2 * 4, stream);
  hipMemsetAsync(possum, 0, NL2 * 12, stream);
  hipMemsetAsync(pord, 0, (size_t)NL2 * 128 * 4, stream);
  hipMemsetAsync(bitmap, 0, (((size_t)NL2 * NL2 + 31) / 32) * 4, stream);
  k_nid<<<cdiv(NL1, 256), 256, 0, stream>>>(pos1, val1, NL1, 1728, 30.f, 8, 512, nid, cnt, possum);
  k_pool_x<<<cdiv((long)NL1 * 128, 256), 256, 0, stream>>>(x2, val1, nid, pord, NL1, 128);
  k_pool_fin<<<cdiv((long)NL2 * 128, 256), 256, 0, stream>>>(pord, cnt, possum, x2p, pos2, val2, NL2, 128);
  k_pool_edges<<<512, 256, 0, stream>>>(src1, dst1, ecnt + 0, E0, nid, NL2, bitmap, src2, dst2, ecnt + 1);

  // ===== Layer 3 (128 -> 256) =====
  k_absmax<<<512, 256, 0, stream>>>(pos2, src2, dst2, ecnt + 1, E0, mbuf + 2);
  k_gemm<<<dim3(4, cdiv(NL2, 64), 8), 256, 0, stream>>>(x2p, W3, xk, NL2, 256, 128, 128, 256, 2048, 128L * 256, 256);
  k_gemm<<<dim3(4, cdiv(NL2, 64), 1), 256, 0, stream>>>(x2p, Wr3, xr, NL2, 256, 128, 128, 256, 256, 0, 0);
  hipMemsetAsync(agg, 0, (size_t)NL2 * 256 * 4, stream);
  hipMemsetAsync(deg, 0, NL2 * 4, stream);
  k_msg<<<2048, 256, 0, stream>>>(pos2, src2, dst2, ecnt + 1, E0, mbuf + 2, xk, agg, deg, 256, 6);
  k_finish<<<cdiv((long)NL2 * 256, 256), 256, 0, stream>>>(agg, deg, xr, b3, x3, NL2, 256);

  // ===== Pool 3 (vs=50, G=5, NC=125) =====
  hipMemsetAsync(cnt, 0, NL3 * 4, stream);
  hipMemsetAsync(possum, 0, NL3 * 12, stream);
  hipMemsetAsync(pord, 0, (size_t)NL3 * 256 * 4, stream);
  hipMemsetAsync(bitmap, 0, (((size_t)NL3 * NL3 + 31) / 32) * 4, stream);
  k_nid<<<cdiv(NL2, 256), 256, 0, stream>>>(pos2, val2, NL2, 512, 50.f, 5, 125, nid, cnt, possum);
  k_pool_x<<<cdiv((long)NL2 * 256, 256), 256, 0, stream>>>(x3, val2, nid, pord, NL2, 256);
  k_pool_fin<<<cdiv((long)NL3 * 256, 256), 256, 0, stream>>>(pord, cnt, possum, x3p, pos3, val3, NL3, 256);
  k_pool_edges<<<512, 256, 0, stream>>>(src2, dst2, ecnt + 1, E0, nid, NL3, bitmap, src3, dst3, ecnt + 2);

  // ===== Layer 4 (256 -> 512) =====
  k_absmax<<<512, 256, 0, stream>>>(pos3, src3, dst3, ecnt + 2, E0, mbuf + 3);
  k_gemm<<<dim3(8, cdiv(NL3, 64), 8), 256, 0, stream>>>(x3p, W4, xk, NL3, 512, 256, 256, 512, 4096, 256L * 512, 512);
  k_gemm<<<dim3(8, cdiv(NL3, 64), 1), 256, 0, stream>>>(x3p, Wr4, xr, NL3, 512, 256, 256, 512, 512, 0, 0);
  hipMemsetAsync(agg, 0, (size_t)NL3 * 512 * 4, stream);
  hipMemsetAsync(deg, 0, NL3 * 4, stream);
  k_msg<<<2048, 256, 0, stream>>>(pos3, src3, dst3, ecnt + 2, E0, mbuf + 3, xk, agg, deg, 512, 7);
  k_finish<<<cdiv((long)NL3 * 512, 256), 256, 0, stream>>>(agg, deg, xr, b4, x4, NL3, 512);

  // ===== Final MaxPoolingX (vs=80, G=3, 27 cells -> 64 slots) + FC =====
  k_fill_neg<<<512, 256, 0, stream>>>(pord, 4 * 64 * 512);
  k_final_pool<<<cdiv((long)NL3 * 512, 256), 256, 0, stream>>>(x4, pos3, val3, pord);
  k_xg_fin<<<512, 256, 0, stream>>>(pord, xg);
  hipMemsetAsync(h, 0, 4096 * 4, stream);
  k_fc1<<<27 * 2 * 8, 128, 0, stream>>>(xg, fw1, h);
  k_fc1fin<<<16, 256, 0, stream>>>(h, fb1);
  k_fc2<<<4, 256, 0, stream>>>(h, fw2, fb2, out);
}

// Round 2
// 804.034 us; speedup vs baseline: 1.0380x; 1.0380x over previous
//
#include <hip/hip_runtime.h>

#define NEGV (-1e30f)

// Problem constants (from setup_inputs): B=4, NP=5000
static constexpr int E0 = 160000;   // edges (fixed array size at every level)
static constexpr int NL0 = 20000;   // nodes level 0
static constexpr int NL1 = 6912;    // 4 * 12^3   (voxel 20)
static constexpr int NL2 = 2048;    // 4 * 8^3    (voxel 30)
static constexpr int NL3 = 500;     // 4 * 5^3    (voxel 50)

// ---------- helpers ----------
__device__ __forceinline__ unsigned f2ord(float f) {
  unsigned u = __float_as_uint(f);
  return (u & 0x80000000u) ? ~u : (u | 0x80000000u);
}
__device__ __forceinline__ float ord2f(unsigned u) {
  unsigned v = (u & 0x80000000u) ? (u & 0x7fffffffu) : ~u;
  return __uint_as_float(v);
}
__device__ __forceinline__ float eluf(float x) { return x > 0.f ? x : expm1f(x); }
__device__ __forceinline__ void basis8(float u0, float u1, float u2, float* w) {
  float a0 = 1.f - u0, a1 = 1.f - u1, a2 = 1.f - u2;
  w[0] = a0*a1*a2; w[1] = a0*a1*u2; w[2] = a0*u1*a2; w[3] = a0*u1*u2;
  w[4] = u0*a1*a2; w[5] = u0*a1*u2; w[6] = u0*u1*a2; w[7] = u0*u1*u2;
}

// ---------- edge convert ----------
__global__ void k_convert(const int* __restrict__ ei, int* __restrict__ s,
                          int* __restrict__ d, int E) {
  int e = blockIdx.x * blockDim.x + threadIdx.x;
  if (e < E) { s[e] = ei[e]; d[e] = ei[E + e]; }
}

// ---------- global max |rel| over valid edges ----------
__global__ void k_absmax(const float* __restrict__ pos, const int* __restrict__ src,
                         const int* __restrict__ dst, const int* __restrict__ ecnt,
                         int ecap, float* __restrict__ m) {
  int n = ecnt ? *ecnt : ecap;
  float v = 0.f;
  for (int e = blockIdx.x * blockDim.x + threadIdx.x; e < n;
       e += gridDim.x * blockDim.x) {
    int s = src[e], d = dst[e];
    #pragma unroll
    for (int c = 0; c < 3; c++)
      v = fmaxf(v, fabsf(pos[s*3+c] - pos[d*3+c]));
  }
  for (int off = 32; off; off >>= 1) v = fmaxf(v, __shfl_down(v, off, 64));
  __shared__ float red[4];
  int lane = threadIdx.x & 63, wv = threadIdx.x >> 6;
  if (lane == 0) red[wv] = v;
  __syncthreads();
  if (threadIdx.x == 0) {
    float mm = fmaxf(fmaxf(red[0], red[1]), fmaxf(red[2], red[3]));
    atomicMax((unsigned*)m, __float_as_uint(mm));
  }
}

// ---------- CSR build: deg -> scan -> scatter ----------
__global__ void k_deg(const int* __restrict__ dst, const int* __restrict__ ecnt,
                      int ecap, int* __restrict__ degi) {
  int n = ecnt ? *ecnt : ecap;
  for (int e = blockIdx.x * blockDim.x + threadIdx.x; e < n;
       e += gridDim.x * blockDim.x)
    atomicAdd(&degi[dst[e]], 1);
}

__global__ __launch_bounds__(1024)
void k_scan(const int* __restrict__ degi, int* __restrict__ rowptr,
            int* __restrict__ cursor, int N) {
  __shared__ int wsum[16];
  __shared__ int woff[16];
  __shared__ int sbase, stot;
  int lane = threadIdx.x & 63, wv = threadIdx.x >> 6;
  if (threadIdx.x == 0) sbase = 0;
  __syncthreads();
  for (int c0 = 0; c0 < N; c0 += 1024) {
    int i = c0 + threadIdx.x;
    int v = (i < N) ? degi[i] : 0;
    int s = v;
    #pragma unroll
    for (int off = 1; off < 64; off <<= 1) {
      int t = __shfl_up(s, off, 64);
      if (lane >= off) s += t;
    }
    if (lane == 63) wsum[wv] = s;
    __syncthreads();
    if (threadIdx.x < 64) {
      int tv = (lane < 16) ? wsum[lane] : 0;
      int ss = tv;
      #pragma unroll
      for (int off = 1; off < 16; off <<= 1) {
        int t = __shfl_up(ss, off, 64);
        if (lane >= off) ss += t;
      }
      if (lane < 16) woff[lane] = ss - tv;
      if (lane == 15) stot = ss;
    }
    __syncthreads();
    int excl = sbase + woff[wv] + s - v;
    if (i < N) { rowptr[i] = excl; cursor[i] = excl; }
    __syncthreads();
    if (threadIdx.x == 0) sbase += stot;
    __syncthreads();
  }
  if (threadIdx.x == 0) rowptr[N] = sbase;
}

__global__ void k_scatter(const int* __restrict__ src, const int* __restrict__ dst,
                          const int* __restrict__ ecnt, int ecap,
                          int* __restrict__ cursor, int* __restrict__ esrc) {
  int n = ecnt ? *ecnt : ecap;
  for (int e = blockIdx.x * blockDim.x + threadIdx.x; e < n;
       e += gridDim.x * blockDim.x) {
    int p = atomicAdd(&cursor[dst[e]], 1);
    esrc[p] = src[e];
  }
}

// ---------- gather: ysx[d, k*Ci+i] = (1/deg) sum_e b_ek x[s_e,i]; ysx[d,8Ci+i]=x[d,i] ----------
__global__ __launch_bounds__(256)
void k_gather(const float* __restrict__ pos, const float* __restrict__ x,
              const int* __restrict__ esrc, const int* __restrict__ rowptr,
              const float* __restrict__ m, float* __restrict__ ysx,
              int N, int Ci, int nchunk) {
  int wid = blockIdx.x * 4 + (threadIdx.x >> 6);
  int lane = threadIdx.x & 63;
  int d = wid / nchunk, ch = wid % nchunk;
  if (d >= N) return;
  int co = ch * 64 + lane;
  float inv = 0.5f / fmaxf(m[0], 1e-9f);
  float pd0 = pos[d*3], pd1 = pos[d*3+1], pd2 = pos[d*3+2];
  int beg = rowptr[d], end = rowptr[d+1];
  float acc[8] = {};
  int s_cur = (beg < end) ? esrc[beg] : 0;
  for (int j = beg; j < end; j++) {
    int s = s_cur;
    s_cur = (j + 1 < end) ? esrc[j + 1] : 0;
    float u0 = (pos[s*3+0] - pd0) * inv + 0.5f;
    float u1 = (pos[s*3+1] - pd1) * inv + 0.5f;
    float u2 = (pos[s*3+2] - pd2) * inv + 0.5f;
    float w[8]; basis8(u0, u1, u2, w);
    float xv = x[(long)s * Ci + co];
    #pragma unroll
    for (int k = 0; k < 8; k++) acc[k] += w[k] * xv;
  }
  float sc = 1.f / fmaxf((float)(end - beg), 1.f);
  long row = (long)d * 9 * Ci;
  #pragma unroll
  for (int k = 0; k < 8; k++) ysx[row + k * Ci + co] = acc[k] * sc;
  ysx[row + 8 * Ci + co] = x[(long)d * Ci + co];
}

// layer-1 (Ci=1): thread per dst
__global__ void k_gather1(const float* __restrict__ pos, const float* __restrict__ x0,
                          const int* __restrict__ esrc, const int* __restrict__ rowptr,
                          const float* __restrict__ m, float* __restrict__ ysx, int N) {
  int d = blockIdx.x * blockDim.x + threadIdx.x;
  if (d >= N) return;
  float inv = 0.5f / fmaxf(m[0], 1e-9f);
  float pd0 = pos[d*3], pd1 = pos[d*3+1], pd2 = pos[d*3+2];
  int beg = rowptr[d], end = rowptr[d+1];
  float acc[8] = {};
  for (int j = beg; j < end; j++) {
    int s = esrc[j];
    float u0 = (pos[s*3+0] - pd0) * inv + 0.5f;
    float u1 = (pos[s*3+1] - pd1) * inv + 0.5f;
    float u2 = (pos[s*3+2] - pd2) * inv + 0.5f;
    float w[8]; basis8(u0, u1, u2, w);
    float xv = x0[s];
    #pragma unroll
    for (int k = 0; k < 8; k++) acc[k] += w[k] * xv;
  }
  float sc = 1.f / fmaxf((float)(end - beg), 1.f);
  #pragma unroll
  for (int k = 0; k < 8; k++) ysx[d * 9 + k] = acc[k] * sc;
  ysx[d * 9 + 8] = x0[d];
}

// ---------- weight concat: Wc = [W (nW) ; Wr (nWr)] ----------
__global__ void k_wcat(const float* __restrict__ W, const float* __restrict__ Wr,
                       float* __restrict__ Wc, int nW, int nWr) {
  int i = blockIdx.x * blockDim.x + threadIdx.x;
  if (i < nW) Wc[i] = W[i];
  else if (i < nW + nWr) Wc[i] = Wr[i - nW];
}

// ---------- tiled fp32 GEMM: C = A @ B, optional K-split (z) with atomic accum ----------
__global__ __launch_bounds__(256)
void k_gemm(const float* __restrict__ A, const float* __restrict__ B,
            float* __restrict__ C, int M, int N, int K,
            int lda, int ldb, int ldc) {
  __shared__ __align__(16) float As[16][68];
  __shared__ __align__(16) float Bs[16][68];
  int m0 = blockIdx.y * 64, n0 = blockIdx.x * 64;
  int ksl = (K + gridDim.z - 1) / gridDim.z;
  int kbeg = blockIdx.z * ksl;
  int kend = min(K, kbeg + ksl);
  bool accum = gridDim.z > 1;
  int t = threadIdx.x;
  int ti = t >> 4, tj = t & 15;
  float acc[4][4] = {};
  for (int kt = kbeg; kt < kend; kt += 16) {
    #pragma unroll
    for (int r = 0; r < 4; r++) {
      int q = t + r * 256;
      int k = q & 15, mm = q >> 4;
      int gm = m0 + mm, gk = kt + k;
      As[k][mm] = (gm < M && gk < kend) ? A[(long)gm * lda + gk] : 0.f;
    }
    #pragma unroll
    for (int r = 0; r < 4; r++) {
      int q = t + r * 256;
      int n = q & 63, k = q >> 6;
      int gk = kt + k, gn = n0 + n;
      Bs[k][n] = (gk < kend && gn < N) ? B[(long)gk * ldb + gn] : 0.f;
    }
    __syncthreads();
    #pragma unroll
    for (int kk = 0; kk < 16; kk++) {
      float4 a = *(const float4*)&As[kk][ti * 4];
      float4 b = *(const float4*)&Bs[kk][tj * 4];
      float av[4] = {a.x, a.y, a.z, a.w}, bv[4] = {b.x, b.y, b.z, b.w};
      #pragma unroll
      for (int i = 0; i < 4; i++)
        #pragma unroll
        for (int j = 0; j < 4; j++) acc[i][j] += av[i] * bv[j];
    }
    __syncthreads();
  }
  #pragma unroll
  for (int i = 0; i < 4; i++) {
    int gm = m0 + ti * 4 + i;
    if (gm >= M) continue;
    #pragma unroll
    for (int j = 0; j < 4; j++) {
      int gn = n0 + tj * 4 + j;
      if (gn >= N) continue;
      if (accum) atomicAdd(&C[(long)gm * ldc + gn], acc[i][j]);
      else C[(long)gm * ldc + gn] = acc[i][j];
    }
  }
}

// ---------- finish conv: out = elu(agg + b) ----------
__global__ void k_finish(const float* __restrict__ agg, const float* __restrict__ b,
                         float* __restrict__ out, long NC, int Co) {
  long idx = (long)blockIdx.x * blockDim.x + threadIdx.x;
  if (idx >= NC) return;
  out[idx] = eluf(agg[idx] + b[idx % Co]);
}

// ---------- voxel id + count + pos sums ----------
__global__ void k_nid(const float* __restrict__ pos, const unsigned char* __restrict__ valid,
                      int Nf, int div, float vs, int G, int NC,
                      int* __restrict__ nid, float* __restrict__ cnt,
                      float* __restrict__ possum) {
  int v = blockIdx.x * blockDim.x + threadIdx.x;
  if (v >= Nf) return;
  float p0 = pos[v*3+0], p1 = pos[v*3+1], p2 = pos[v*3+2];
  int c0 = (int)floorf(p0 / vs); c0 = c0 < 0 ? 0 : (c0 > G-1 ? G-1 : c0);
  int c1 = (int)floorf(p1 / vs); c1 = c1 < 0 ? 0 : (c1 > G-1 ? G-1 : c1);
  int c2 = (int)floorf(p2 / vs); c2 = c2 < 0 ? 0 : (c2 > G-1 ? G-1 : c2);
  int id = (v / div) * NC + (c0 * G + c1) * G + c2;
  nid[v] = id;
  if (valid && !valid[v]) return;
  atomicAdd(&cnt[id], 1.f);
  atomicAdd(&possum[id*3+0], p0);
  atomicAdd(&possum[id*3+1], p1);
  atomicAdd(&possum[id*3+2], p2);
}

__global__ void k_pool_x(const float* __restrict__ x, const unsigned char* __restrict__ valid,
                         const int* __restrict__ nid, unsigned* __restrict__ pord,
                         int Nf, int Cf) {
  long idx = (long)blockIdx.x * blockDim.x + threadIdx.x;
  if (idx >= (long)Nf * Cf) return;
  int v = (int)(idx / Cf), o = (int)(idx % Cf);
  if (valid && !valid[v]) return;
  atomicMax(&pord[(long)nid[v] * Cf + o], f2ord(x[idx]));
}

__global__ void k_pool_fin(const unsigned* __restrict__ pord, const float* __restrict__ cnt,
                           const float* __restrict__ possum, float* __restrict__ xp,
                           float* __restrict__ posp, unsigned char* __restrict__ validp,
                           int Nn, int Cf) {
  long idx = (long)blockIdx.x * blockDim.x + threadIdx.x;
  if (idx >= (long)Nn * Cf) return;
  int n = (int)(idx / Cf), o = (int)(idx % Cf);
  float c = cnt[n];
  xp[idx] = (c > 0.f) ? ord2f(pord[idx]) : 0.f;
  if (o == 0) {
    validp[n] = (c > 0.f) ? 1 : 0;
    float ic = 1.f / fmaxf(c, 1.f);
    posp[n*3+0] = possum[n*3+0] * ic;
    posp[n*3+1] = possum[n*3+1] * ic;
    posp[n*3+2] = possum[n*3+2] * ic;
  }
}

// ---------- edge coarsening with bitmap dedup + compaction ----------
__global__ void k_pool_edges(const int* __restrict__ srcf, const int* __restrict__ dstf,
                             const int* __restrict__ ecntf, int ecap,
                             const int* __restrict__ nid, int Nn,
                             unsigned* __restrict__ bitmap,
                             int* __restrict__ srcc, int* __restrict__ dstc,
                             int* __restrict__ ecntc) {
  int n = ecntf ? *ecntf : ecap;
  for (int e = blockIdx.x * blockDim.x + threadIdx.x; e < n;
       e += gridDim.x * blockDim.x) {
    int s2 = nid[srcf[e]], d2 = nid[dstf[e]];
    if (s2 == d2) continue;
    unsigned key = (unsigned)s2 * (unsigned)Nn + (unsigned)d2;
    unsigned bit = 1u << (key & 31);
    unsigned old = atomicOr(&bitmap[key >> 5], bit);
    if (!(old & bit)) {
      int p = atomicAdd(ecntc, 1);
      srcc[p] = s2; dstc[p] = d2;
    }
  }
}

// ---------- final pooling + FC ----------
__global__ void k_fill_neg(unsigned* __restrict__ p, int n) {
  int i = blockIdx.x * blockDim.x + threadIdx.x;
  if (i < n) p[i] = f2ord(NEGV);
}

__global__ void k_final_pool(const float* __restrict__ x, const float* __restrict__ pos,
                             const unsigned char* __restrict__ valid,
                             unsigned* __restrict__ xg_ord) {
  long idx = (long)blockIdx.x * blockDim.x + threadIdx.x;
  if (idx >= (long)NL3 * 512) return;
  int v = (int)(idx >> 9), o = (int)(idx & 511);
  if (!valid[v]) return;
  const float vs = 80.f; const int G = 3;
  float p0 = pos[v*3+0], p1 = pos[v*3+1], p2 = pos[v*3+2];
  int c0 = (int)floorf(p0 / vs); c0 = c0 < 0 ? 0 : (c0 > G-1 ? G-1 : c0);
  int c1 = (int)floorf(p1 / vs); c1 = c1 < 0 ? 0 : (c1 > G-1 ? G-1 : c1);
  int c2 = (int)floorf(p2 / vs); c2 = c2 < 0 ? 0 : (c2 > G-1 ? G-1 : c2);
  int cell = (c0 * G + c1) * G + c2;
  int cluster = (v / 125) * 64 + cell;
  atomicMax(&xg_ord[cluster * 512 + o], f2ord(x[idx]));
}

__global__ void k_xg_fin(const unsigned* __restrict__ xg_ord, float* __restrict__ xg) {
  int i = blockIdx.x * blockDim.x + threadIdx.x;
  if (i >= 4 * 64 * 512) return;
  float f = ord2f(xg_ord[i]);
  xg[i] = (f <= NEGV * 0.5f) ? 0.f : f;
}

// FC1: only cells 0..26 can be nonzero -> skip 37/64 of the 134MB weight.
__global__ __launch_bounds__(128)
void k_fc1(const float* __restrict__ xg, const float* __restrict__ w,
           float* __restrict__ h) {
  int cellhalf = blockIdx.x >> 3, jb = blockIdx.x & 7;
  int cell = cellhalf >> 1, half = cellhalf & 1;
  int j = jb * 128 + threadIdx.x;
  __shared__ float xs[4][256];
  for (int q = threadIdx.x; q < 1024; q += 128) {
    int b = q >> 8, ci = q & 255;
    xs[b][ci] = xg[((b * 64 + cell) << 9) + half * 256 + ci];
  }
  __syncthreads();
  float a0 = 0, a1 = 0, a2 = 0, a3 = 0;
  int cbase = cell * 512 + half * 256;
  for (int ci = 0; ci < 256; ci++) {
    float ww = w[(long)(cbase + ci) * 1024 + j];
    a0 += xs[0][ci] * ww; a1 += xs[1][ci] * ww;
    a2 += xs[2][ci] * ww; a3 += xs[3][ci] * ww;
  }
  atomicAdd(&h[j], a0);        atomicAdd(&h[1024 + j], a1);
  atomicAdd(&h[2048 + j], a2); atomicAdd(&h[3072 + j], a3);
}

__global__ void k_fc1fin(float* __restrict__ h, const float* __restrict__ b) {
  int i = blockIdx.x * blockDim.x + threadIdx.x;
  if (i < 4096) h[i] = eluf(h[i] + b[i & 1023]);
}

__global__ void k_fc2(const float* __restrict__ h, const float* __restrict__ w,
                      const float* __restrict__ b, float* __restrict__ out) {
  int bb = blockIdx.x, t = threadIdx.x;
  float a = 0;
  for (int j = t; j < 1024; j += 256) a += h[bb * 1024 + j] * w[j];
  for (int off = 32; off; off >>= 1) a += __shfl_down(a, off, 64);
  __shared__ float red[4];
  int lane = t & 63, wv = t >> 6;
  if (lane == 0) red[wv] = a;
  __syncthreads();
  if (t == 0) out[bb] = eluf(red[0] + red[1] + red[2] + red[3] + b[0]);
}

// =======================================================================
extern "C" void kernel_launch(void* const* d_in, const int* in_sizes, int n_in,
                              void* d_out, int out_size, void* d_ws, size_t ws_size,
                              hipStream_t stream) {
  const float* x0   = (const float*)d_in[0];
  const float* pos0 = (const float*)d_in[1];
  const int*   ei   = (const int*)d_in[2];
  const float* W1 = (const float*)d_in[4],  *Wr1 = (const float*)d_in[5],  *b1 = (const float*)d_in[6];
  const float* W2 = (const float*)d_in[7],  *Wr2 = (const float*)d_in[8],  *b2 = (const float*)d_in[9];
  const float* W3 = (const float*)d_in[10], *Wr3 = (const float*)d_in[11], *b3 = (const float*)d_in[12];
  const float* W4 = (const float*)d_in[13], *Wr4 = (const float*)d_in[14], *b4 = (const float*)d_in[15];
  const float* fw1 = (const float*)d_in[16], *fb1 = (const float*)d_in[17];
  const float* fw2 = (const float*)d_in[18], *fb2 = (const float*)d_in[19];
  float* out = (float*)d_out;

  // ---- workspace layout ----
  char* ws = (char*)d_ws;
  size_t off = 0;
  auto alloc = [&](size_t bytes) -> void* {
    off = (off + 255) & ~(size_t)255;
    void* p = ws + off; off += bytes; return p;
  };
  int* src0 = (int*)alloc(E0 * 4); int* dst0 = (int*)alloc(E0 * 4);
  int* src1 = (int*)alloc(E0 * 4); int* dst1 = (int*)alloc(E0 * 4);
  int* src2 = (int*)alloc(E0 * 4); int* dst2 = (int*)alloc(E0 * 4);
  int* src3 = (int*)alloc(E0 * 4); int* dst3 = (int*)alloc(E0 * 4);
  float* x1  = (float*)alloc((size_t)NL0 * 64 * 4);
  float* x1p = (float*)alloc((size_t)NL1 * 64 * 4);
  float* x2  = (float*)alloc((size_t)NL1 * 128 * 4);
  float* x2p = (float*)alloc((size_t)NL2 * 128 * 4);
  float* x3  = (float*)alloc((size_t)NL2 * 256 * 4);
  float* x3p = (float*)alloc((size_t)NL3 * 256 * 4);
  float* x4  = (float*)alloc((size_t)NL3 * 512 * 4);
  float* pos1 = (float*)alloc(NL1 * 12);
  float* pos2 = (float*)alloc(NL2 * 12);
  float* pos3 = (float*)alloc(NL3 * 12);
  unsigned char* val1 = (unsigned char*)alloc(NL1);
  unsigned char* val2 = (unsigned char*)alloc(NL2);
  unsigned char* val3 = (unsigned char*)alloc(NL3);
  float* cnt    = (float*)alloc(NL1 * 4);
  float* possum = (float*)alloc(NL1 * 12);
  unsigned* pord = (unsigned*)alloc((size_t)NL1 * 64 * 4);   // also reused as xg_ord
  float* ysx = (float*)alloc((size_t)NL1 * 576 * 4);         // max(6912*576, 2048*1152, 500*2304, 20000*9)
  float* wcat = (float*)alloc((size_t)2304 * 512 * 4);       // max 9*256 x 512
  float* agg = (float*)alloc((size_t)NL0 * 64 * 4);          // max N*Co = 20000*64
  int* degi   = (int*)alloc(NL0 * 4);
  int* rowptr = (int*)alloc((NL0 + 1) * 4);
  int* cursor = (int*)alloc(NL0 * 4);
  int* esrc   = (int*)alloc(E0 * 4);
  size_t bmwords = ((size_t)NL1 * NL1 + 31) / 32;
  unsigned* bitmap = (unsigned*)alloc(bmwords * 4);
  float* mbuf = (float*)alloc(16);
  int* ecnt   = (int*)alloc(16);
  float* xg   = (float*)alloc(4 * 64 * 512 * 4);
  float* h    = (float*)alloc(4096 * 4);
  (void)ws_size; (void)in_sizes; (void)n_in; (void)out_size;

  auto cdiv = [](long a, long b) { return (int)((a + b - 1) / b); };

  hipMemsetAsync(mbuf, 0, 16, stream);
  hipMemsetAsync(ecnt, 0, 16, stream);
  k_convert<<<cdiv(E0, 256), 256, 0, stream>>>(ei, src0, dst0, E0);

  // ===== CSR level 0 =====
  hipMemsetAsync(degi, 0, NL0 * 4, stream);
  k_deg<<<512, 256, 0, stream>>>(dst0, nullptr, E0, degi);
  k_scan<<<1, 1024, 0, stream>>>(degi, rowptr, cursor, NL0);
  k_scatter<<<512, 256, 0, stream>>>(src0, dst0, nullptr, E0, cursor, esrc);

  // ===== Layer 1 (1 -> 64) =====
  k_absmax<<<512, 256, 0, stream>>>(pos0, src0, dst0, nullptr, E0, mbuf + 0);
  k_wcat<<<cdiv(9 * 64, 256), 256, 0, stream>>>(W1, Wr1, wcat, 8 * 64, 64);
  k_gather1<<<cdiv(NL0, 256), 256, 0, stream>>>(pos0, x0, esrc, rowptr, mbuf + 0, ysx, NL0);
  k_gemm<<<dim3(1, cdiv(NL0, 64), 1), 256, 0, stream>>>(ysx, wcat, agg, NL0, 64, 9, 9, 64, 64);
  k_finish<<<cdiv((long)NL0 * 64, 256), 256, 0, stream>>>(agg, b1, x1, (long)NL0 * 64, 64);

  // ===== Pool 1 (vs=20, G=12, NC=1728) =====
  hipMemsetAsync(cnt, 0, NL1 * 4, stream);
  hipMemsetAsync(possum, 0, NL1 * 12, stream);
  hipMemsetAsync(pord, 0, (size_t)NL1 * 64 * 4, stream);
  hipMemsetAsync(bitmap, 0, bmwords * 4, stream);
  k_nid<<<cdiv(NL0, 256), 256, 0, stream>>>(pos0, nullptr, NL0, 5000, 20.f, 12, 1728, degi /*reuse as nid*/, cnt, possum);
  k_pool_x<<<cdiv((long)NL0 * 64, 256), 256, 0, stream>>>(x1, nullptr, degi, pord, NL0, 64);
  k_pool_fin<<<cdiv((long)NL1 * 64, 256), 256, 0, stream>>>(pord, cnt, possum, x1p, pos1, val1, NL1, 64);
  k_pool_edges<<<512, 256, 0, stream>>>(src0, dst0, nullptr, E0, degi, NL1, bitmap, src1, dst1, ecnt + 0);

  // ===== CSR level 1 =====
  hipMemsetAsync(degi, 0, NL1 * 4, stream);
  k_deg<<<512, 256, 0, stream>>>(dst1, ecnt + 0, E0, degi);
  k_scan<<<1, 1024, 0, stream>>>(degi, rowptr, cursor, NL1);
  k_scatter<<<512, 256, 0, stream>>>(src1, dst1, ecnt + 0, E0, cursor, esrc);

  // ===== Layer 2 (64 -> 128) =====
  k_absmax<<<512, 256, 0, stream>>>(pos1, src1, dst1, ecnt + 0, E0, mbuf + 1);
  k_wcat<<<cdiv(9 * 64 * 128, 256), 256, 0, stream>>>(W2, Wr2, wcat, 8 * 64 * 128, 64 * 128);
  k_gather<<<cdiv(NL1, 4), 256, 0, stream>>>(pos1, x1p, esrc, rowptr, mbuf + 1, ysx, NL1, 64, 1);
  k_gemm<<<dim3(2, cdiv(NL1, 64), 1), 256, 0, stream>>>(ysx, wcat, agg, NL1, 128, 576, 576, 128, 128);
  k_finish<<<cdiv((long)NL1 * 128, 256), 256, 0, stream>>>(agg, b2, x2, (long)NL1 * 128, 128);

  // ===== Pool 2 (vs=30, G=8, NC=512) =====
  hipMemsetAsync(cnt, 0, NL2 * 4, stream);
  hipMemsetAsync(possum, 0, NL2 * 12, stream);
  hipMemsetAsync(pord, 0, (size_t)NL2 * 128 * 4, stream);
  hipMemsetAsync(bitmap, 0, (((size_t)NL2 * NL2 + 31) / 32) * 4, stream);
  k_nid<<<cdiv(NL1, 256), 256, 0, stream>>>(pos1, val1, NL1, 1728, 30.f, 8, 512, degi, cnt, possum);
  k_pool_x<<<cdiv((long)NL1 * 128, 256), 256, 0, stream>>>(x2, val1, degi, pord, NL1, 128);
  k_pool_fin<<<cdiv((long)NL2 * 128, 256), 256, 0, stream>>>(pord, cnt, possum, x2p, pos2, val2, NL2, 128);
  k_pool_edges<<<512, 256, 0, stream>>>(src1, dst1, ecnt + 0, E0, degi, NL2, bitmap, src2, dst2, ecnt + 1);

  // ===== CSR level 2 =====
  hipMemsetAsync(degi, 0, NL2 * 4, stream);
  k_deg<<<512, 256, 0, stream>>>(dst2, ecnt + 1, E0, degi);
  k_scan<<<1, 1024, 0, stream>>>(degi, rowptr, cursor, NL2);
  k_scatter<<<512, 256, 0, stream>>>(src2, dst2, ecnt + 1, E0, cursor, esrc);

  // ===== Layer 3 (128 -> 256) =====
  k_absmax<<<512, 256, 0, stream>>>(pos2, src2, dst2, ecnt + 1, E0, mbuf + 2);
  k_wcat<<<cdiv(9 * 128 * 256, 256), 256, 0, stream>>>(W3, Wr3, wcat, 8 * 128 * 256, 128 * 256);
  k_gather<<<cdiv(NL2 * 2, 4), 256, 0, stream>>>(pos2, x2p, esrc, rowptr, mbuf + 2, ysx, NL2, 128, 2);
  hipMemsetAsync(agg, 0, (size_t)NL2 * 256 * 4, stream);
  k_gemm<<<dim3(4, cdiv(NL2, 64), 2), 256, 0, stream>>>(ysx, wcat, agg, NL2, 256, 1152, 1152, 256, 256);
  k_finish<<<cdiv((long)NL2 * 256, 256), 256, 0, stream>>>(agg, b3, x3, (long)NL2 * 256, 256);

  // ===== Pool 3 (vs=50, G=5, NC=125) =====
  hipMemsetAsync(cnt, 0, NL3 * 4, stream);
  hipMemsetAsync(possum, 0, NL3 * 12, stream);
  hipMemsetAsync(pord, 0, (size_t)NL3 * 256 * 4, stream);
  hipMemsetAsync(bitmap, 0, (((size_t)NL3 * NL3 + 31) / 32) * 4, stream);
  k_nid<<<cdiv(NL2, 256), 256, 0, stream>>>(pos2, val2, NL2, 512, 50.f, 5, 125, degi, cnt, possum);
  k_pool_x<<<cdiv((long)NL2 * 256, 256), 256, 0, stream>>>(x3, val2, degi, pord, NL2, 256);
  k_pool_fin<<<cdiv((long)NL3 * 256, 256), 256, 0, stream>>>(pord, cnt, possum, x3p, pos3, val3, NL3, 256);
  k_pool_edges<<<512, 256, 0, stream>>>(src2, dst2, ecnt + 1, E0, degi, NL3, bitmap, src3, dst3, ecnt + 2);

  // ===== CSR level 3 =====
  hipMemsetAsync(degi, 0, NL3 * 4, stream);
  k_deg<<<512, 256, 0, stream>>>(dst3, ecnt + 2, E0, degi);
  k_scan<<<1, 1024, 0, stream>>>(degi, rowptr, cursor, NL3);
  k_scatter<<<512, 256, 0, stream>>>(src3, dst3, ecnt + 2, E0, cursor, esrc);

  // ===== Layer 4 (256 -> 512) =====
  k_absmax<<<512, 256, 0, stream>>>(pos3, src3, dst3, ecnt + 2, E0, mbuf + 3);
  k_wcat<<<cdiv(9 * 256 * 512, 256), 256, 0, stream>>>(W4, Wr4, wcat, 8 * 256 * 512, 256 * 512);
  k_gather<<<cdiv(NL3 * 4, 4), 256, 0, stream>>>(pos3, x3p, esrc, rowptr, mbuf + 3, ysx, NL3, 256, 4);
  hipMemsetAsync(agg, 0, (size_t)NL3 * 512 * 4, stream);
  k_gemm<<<dim3(8, cdiv(NL3, 64), 4), 256, 0, stream>>>(ysx, wcat, agg, NL3, 512, 2304, 2304, 512, 512);
  k_finish<<<cdiv((long)NL3 * 512, 256), 256, 0, stream>>>(agg, b4, x4, (long)NL3 * 512, 512);

  // ===== Final MaxPoolingX (vs=80, G=3, 27 cells -> 64 slots) + FC =====
  k_fill_neg<<<512, 256, 0, stream>>>(pord, 4 * 64 * 512);
  k_final_pool<<<cdiv((long)NL3 * 512, 256), 256, 0, stream>>>(x4, pos3, val3, pord);
  k_xg_fin<<<512, 256, 0, stream>>>(pord, xg);
  hipMemsetAsync(h, 0, 4096 * 4, stream);
  k_fc1<<<27 * 2 * 8, 128, 0, stream>>>(xg, fw1, h);
  k_fc1fin<<<16, 256, 0, stream>>>(h, fb1);
  k_fc2<<<4, 256, 0, stream>>>(h, fw2, fb2, out);
}

// Round 3
// 559.255 us; speedup vs baseline: 1.4923x; 1.4377x over previous
//
#include <hip/hip_runtime.h>

// Problem constants (from setup_inputs): B=4, NP=5000
static constexpr int E0 = 160000;   // edges (fixed array size at every level)
static constexpr int NL0 = 20000;   // nodes level 0
static constexpr int NL1 = 6912;    // 4 * 12^3   (voxel 20)
static constexpr int NL2 = 2048;    // 4 * 8^3    (voxel 30)
static constexpr int NL3 = 500;     // 4 * 5^3    (voxel 50)

// ---------- helpers ----------
__device__ __forceinline__ unsigned f2ord(float f) {
  unsigned u = __float_as_uint(f);
  return (u & 0x80000000u) ? ~u : (u | 0x80000000u);
}
__device__ __forceinline__ float ord2f(unsigned u) {
  unsigned v = (u & 0x80000000u) ? (u & 0x7fffffffu) : ~u;
  return __uint_as_float(v);
}
__device__ __forceinline__ float eluf(float x) { return x > 0.f ? x : expm1f(x); }
__device__ __forceinline__ void basis8(float u0, float u1, float u2, float* w) {
  float a0 = 1.f - u0, a1 = 1.f - u1, a2 = 1.f - u2;
  w[0] = a0*a1*a2; w[1] = a0*a1*u2; w[2] = a0*u1*a2; w[3] = a0*u1*u2;
  w[4] = u0*a1*a2; w[5] = u0*a1*u2; w[6] = u0*u1*a2; w[7] = u0*u1*u2;
}

// ---------- global max |rel| over edges (level 0 only) ----------
__global__ void k_absmax(const float* __restrict__ pos, const int* __restrict__ src,
                         const int* __restrict__ dst, int n, float* __restrict__ m) {
  float v = 0.f;
  for (int e = blockIdx.x * blockDim.x + threadIdx.x; e < n;
       e += gridDim.x * blockDim.x) {
    int s = src[e], d = dst[e];
    #pragma unroll
    for (int c = 0; c < 3; c++)
      v = fmaxf(v, fabsf(pos[s*3+c] - pos[d*3+c]));
  }
  for (int off = 32; off; off >>= 1) v = fmaxf(v, __shfl_down(v, off, 64));
  __shared__ float red[4];
  int lane = threadIdx.x & 63, wv = threadIdx.x >> 6;
  if (lane == 0) red[wv] = v;
  __syncthreads();
  if (threadIdx.x == 0) {
    float mm = fmaxf(fmaxf(red[0], red[1]), fmaxf(red[2], red[3]));
    atomicMax((unsigned*)m, __float_as_uint(mm));  // non-negative: uint-ordered
  }
}

// ---------- CSR build: deg -> scan -> scatter ----------
__global__ void k_deg(const int* __restrict__ dst, int n, int* __restrict__ degi) {
  for (int e = blockIdx.x * blockDim.x + threadIdx.x; e < n;
       e += gridDim.x * blockDim.x)
    atomicAdd(&degi[dst[e]], 1);
}

__global__ __launch_bounds__(1024)
void k_scan(const int* __restrict__ degi, int* __restrict__ rowptr,
            int* __restrict__ cursor, int N) {
  __shared__ int wsum[16];
  __shared__ int woff[16];
  __shared__ int sbase, stot;
  int lane = threadIdx.x & 63, wv = threadIdx.x >> 6;
  if (threadIdx.x == 0) sbase = 0;
  __syncthreads();
  for (int c0 = 0; c0 < N; c0 += 1024) {
    int i = c0 + threadIdx.x;
    int v = (i < N) ? degi[i] : 0;
    int s = v;
    #pragma unroll
    for (int off = 1; off < 64; off <<= 1) {
      int t = __shfl_up(s, off, 64);
      if (lane >= off) s += t;
    }
    if (lane == 63) wsum[wv] = s;
    __syncthreads();
    if (threadIdx.x < 64) {
      int tv = (lane < 16) ? wsum[lane] : 0;
      int ss = tv;
      #pragma unroll
      for (int off = 1; off < 16; off <<= 1) {
        int t = __shfl_up(ss, off, 64);
        if (lane >= off) ss += t;
      }
      if (lane < 16) woff[lane] = ss - tv;
      if (lane == 15) stot = ss;
    }
    __syncthreads();
    int excl = sbase + woff[wv] + s - v;
    if (i < N) { rowptr[i] = excl; cursor[i] = excl; }
    __syncthreads();
    if (threadIdx.x == 0) sbase += stot;
    __syncthreads();
  }
  if (threadIdx.x == 0) rowptr[N] = sbase;
}

__global__ void k_scatter(const int* __restrict__ src, const int* __restrict__ dst,
                          const int* __restrict__ ecnt, int ecap,
                          int* __restrict__ cursor, int* __restrict__ esrc) {
  int n = ecnt ? *ecnt : ecap;
  for (int e = blockIdx.x * blockDim.x + threadIdx.x; e < n;
       e += gridDim.x * blockDim.x) {
    int p = atomicAdd(&cursor[dst[e]], 1);
    esrc[p] = src[e];
  }
}

// ---------- gather: ysx[d, k*Ci+i] = (1/deg) sum_e b_ek x[s_e,i]; ysx[d,8Ci+i]=x[d,i] ----------
__global__ __launch_bounds__(256)
void k_gather(const float* __restrict__ pos, const float* __restrict__ x,
              const int* __restrict__ esrc, const int* __restrict__ rowptr,
              const float* __restrict__ m, float* __restrict__ ysx,
              int N, int Ci, int nchunk) {
  int wid = blockIdx.x * 4 + (threadIdx.x >> 6);
  int lane = threadIdx.x & 63;
  int d = wid / nchunk, ch = wid % nchunk;
  if (d >= N) return;
  int co = ch * 64 + lane;
  float inv = 0.5f / fmaxf(m[0], 1e-9f);
  float pd0 = pos[d*3], pd1 = pos[d*3+1], pd2 = pos[d*3+2];
  int beg = rowptr[d], end = rowptr[d+1];
  float acc[8] = {};
  int s_cur = (beg < end) ? esrc[beg] : 0;
  for (int j = beg; j < end; j++) {
    int s = s_cur;
    s_cur = (j + 1 < end) ? esrc[j + 1] : 0;
    float u0 = (pos[s*3+0] - pd0) * inv + 0.5f;
    float u1 = (pos[s*3+1] - pd1) * inv + 0.5f;
    float u2 = (pos[s*3+2] - pd2) * inv + 0.5f;
    float w[8]; basis8(u0, u1, u2, w);
    float xv = x[(long)s * Ci + co];
    #pragma unroll
    for (int k = 0; k < 8; k++) acc[k] += w[k] * xv;
  }
  float sc = 1.f / fmaxf((float)(end - beg), 1.f);
  long row = (long)d * 9 * Ci;
  #pragma unroll
  for (int k = 0; k < 8; k++) ysx[row + k * Ci + co] = acc[k] * sc;
  ysx[row + 8 * Ci + co] = x[(long)d * Ci + co];
}

// layer-1 (Ci=1): thread per dst
__global__ void k_gather1(const float* __restrict__ pos, const float* __restrict__ x0,
                          const int* __restrict__ esrc, const int* __restrict__ rowptr,
                          const float* __restrict__ m, float* __restrict__ ysx, int N) {
  int d = blockIdx.x * blockDim.x + threadIdx.x;
  if (d >= N) return;
  float inv = 0.5f / fmaxf(m[0], 1e-9f);
  float pd0 = pos[d*3], pd1 = pos[d*3+1], pd2 = pos[d*3+2];
  int beg = rowptr[d], end = rowptr[d+1];
  float acc[8] = {};
  for (int j = beg; j < end; j++) {
    int s = esrc[j];
    float u0 = (pos[s*3+0] - pd0) * inv + 0.5f;
    float u1 = (pos[s*3+1] - pd1) * inv + 0.5f;
    float u2 = (pos[s*3+2] - pd2) * inv + 0.5f;
    float w[8]; basis8(u0, u1, u2, w);
    float xv = x0[s];
    #pragma unroll
    for (int k = 0; k < 8; k++) acc[k] += w[k] * xv;
  }
  float sc = 1.f / fmaxf((float)(end - beg), 1.f);
  #pragma unroll
  for (int k = 0; k < 8; k++) ysx[d * 9 + k] = acc[k] * sc;
  ysx[d * 9 + 8] = x0[d];
}

// ---------- all 4 weight concats in one kernel ----------
__global__ void k_wcat_all(const float* __restrict__ W1, const float* __restrict__ Wr1,
                           const float* __restrict__ W2, const float* __restrict__ Wr2,
                           const float* __restrict__ W3, const float* __restrict__ Wr3,
                           const float* __restrict__ W4, const float* __restrict__ Wr4,
                           float* __restrict__ wc1, float* __restrict__ wc2,
                           float* __restrict__ wc3, float* __restrict__ wc4) {
  const int n1w = 8*64, n1r = 64;
  const int n2w = 8*64*128, n2r = 64*128;
  const int n3w = 8*128*256, n3r = 128*256;
  const int n4w = 8*256*512, n4r = 256*512;
  int tot = (n1w+n1r) + (n2w+n2r) + (n3w+n3r) + (n4w+n4r);
  for (int i = blockIdx.x * blockDim.x + threadIdx.x; i < tot;
       i += gridDim.x * blockDim.x) {
    int q = i;
    if (q < n1w + n1r) { wc1[q] = (q < n1w) ? W1[q] : Wr1[q - n1w]; continue; }
    q -= n1w + n1r;
    if (q < n2w + n2r) { wc2[q] = (q < n2w) ? W2[q] : Wr2[q - n2w]; continue; }
    q -= n2w + n2r;
    if (q < n3w + n3r) { wc3[q] = (q < n3w) ? W3[q] : Wr3[q - n3w]; continue; }
    q -= n3w + n3r;
    wc4[q] = (q < n4w) ? W4[q] : Wr4[q - n4w];
  }
}

// ---------- tiled fp32 GEMM, split-K partials OR fused bias+ELU ----------
__global__ __launch_bounds__(256)
void k_gemm(const float* __restrict__ A, const float* __restrict__ B,
            float* __restrict__ C, int M, int N, int K,
            int lda, int ldb, int ldc, long zstride, const float* __restrict__ bias) {
  __shared__ __align__(16) float As[16][68];
  __shared__ __align__(16) float Bs[16][68];
  int m0 = blockIdx.y * 64, n0 = blockIdx.x * 64;
  int ksl = (K + gridDim.z - 1) / gridDim.z;
  int kbeg = blockIdx.z * ksl;
  int kend = min(K, kbeg + ksl);
  int t = threadIdx.x;
  int ti = t >> 4, tj = t & 15;
  float acc[4][4] = {};
  for (int kt = kbeg; kt < kend; kt += 16) {
    #pragma unroll
    for (int r = 0; r < 4; r++) {
      int q = t + r * 256;
      int k = q & 15, mm = q >> 4;
      int gm = m0 + mm, gk = kt + k;
      As[k][mm] = (gm < M && gk < kend) ? A[(long)gm * lda + gk] : 0.f;
    }
    #pragma unroll
    for (int r = 0; r < 4; r++) {
      int q = t + r * 256;
      int n = q & 63, k = q >> 6;
      int gk = kt + k, gn = n0 + n;
      Bs[k][n] = (gk < kend && gn < N) ? B[(long)gk * ldb + gn] : 0.f;
    }
    __syncthreads();
    #pragma unroll
    for (int kk = 0; kk < 16; kk++) {
      float4 a = *(const float4*)&As[kk][ti * 4];
      float4 b = *(const float4*)&Bs[kk][tj * 4];
      float av[4] = {a.x, a.y, a.z, a.w}, bv[4] = {b.x, b.y, b.z, b.w};
      #pragma unroll
      for (int i = 0; i < 4; i++)
        #pragma unroll
        for (int j = 0; j < 4; j++) acc[i][j] += av[i] * bv[j];
    }
    __syncthreads();
  }
  float* Co = C + zstride * blockIdx.z;
  #pragma unroll
  for (int i = 0; i < 4; i++) {
    int gm = m0 + ti * 4 + i;
    if (gm >= M) continue;
    #pragma unroll
    for (int j = 0; j < 4; j++) {
      int gn = n0 + tj * 4 + j;
      if (gn >= N) continue;
      float v = acc[i][j];
      if (bias) v = eluf(v + bias[gn]);
      Co[(long)gm * ldc + gn] = v;
    }
  }
}

// ---------- reduce split-K partials + bias + ELU ----------
__global__ void k_reduce(const float* __restrict__ Cp, const float* __restrict__ bias,
                         float* __restrict__ out, long MN, int N, int z) {
  long idx = (long)blockIdx.x * blockDim.x + threadIdx.x;
  if (idx >= MN) return;
  float s = 0.f;
  for (int q = 0; q < z; q++) s += Cp[q * MN + idx];
  out[idx] = eluf(s + bias[idx % N]);
}

// ---------- voxel id + count + pos sums ----------
__global__ void k_nid(const float* __restrict__ pos, const unsigned char* __restrict__ valid,
                      int Nf, int div, float vs, int G, int NC,
                      int* __restrict__ nid, float* __restrict__ cnt,
                      float* __restrict__ possum) {
  int v = blockIdx.x * blockDim.x + threadIdx.x;
  if (v >= Nf) return;
  float p0 = pos[v*3+0], p1 = pos[v*3+1], p2 = pos[v*3+2];
  int c0 = (int)floorf(p0 / vs); c0 = c0 < 0 ? 0 : (c0 > G-1 ? G-1 : c0);
  int c1 = (int)floorf(p1 / vs); c1 = c1 < 0 ? 0 : (c1 > G-1 ? G-1 : c1);
  int c2 = (int)floorf(p2 / vs); c2 = c2 < 0 ? 0 : (c2 > G-1 ? G-1 : c2);
  int id = (v / div) * NC + (c0 * G + c1) * G + c2;
  nid[v] = id;
  if (valid && !valid[v]) return;
  atomicAdd(&cnt[id], 1.f);
  atomicAdd(&possum[id*3+0], p0);
  atomicAdd(&possum[id*3+1], p1);
  atomicAdd(&possum[id*3+2], p2);
}

__global__ void k_pool_x(const float* __restrict__ x, const unsigned char* __restrict__ valid,
                         const int* __restrict__ nid, unsigned* __restrict__ pord,
                         int Nf, int Cf) {
  long idx = (long)blockIdx.x * blockDim.x + threadIdx.x;
  if (idx >= (long)Nf * Cf) return;
  int v = (int)(idx / Cf);
  if (valid && !valid[v]) return;
  int o = (int)(idx % Cf);
  atomicMax(&pord[(long)nid[v] * Cf + o], f2ord(x[idx]));
}

__global__ void k_pool_fin(const unsigned* __restrict__ pord, const float* __restrict__ cnt,
                           const float* __restrict__ possum, float* __restrict__ xp,
                           float* __restrict__ posp, unsigned char* __restrict__ validp,
                           int Nn, int Cf) {
  long idx = (long)blockIdx.x * blockDim.x + threadIdx.x;
  if (idx >= (long)Nn * Cf) return;
  int n = (int)(idx / Cf), o = (int)(idx % Cf);
  float c = cnt[n];
  xp[idx] = (c > 0.f) ? ord2f(pord[idx]) : 0.f;
  if (o == 0) {
    validp[n] = (c > 0.f) ? 1 : 0;
    float ic = 1.f / fmaxf(c, 1.f);
    posp[n*3+0] = possum[n*3+0] * ic;
    posp[n*3+1] = possum[n*3+1] * ic;
    posp[n*3+2] = possum[n*3+2] * ic;
  }
}

// ---------- edge coarsening: dedup + compaction + next-level deg + next-level absmax ----------
__global__ void k_pool_edges(const int* __restrict__ srcf, const int* __restrict__ dstf,
                             const int* __restrict__ ecntf, int ecap,
                             const int* __restrict__ nid, int Nn,
                             unsigned* __restrict__ bitmap,
                             int* __restrict__ srcc, int* __restrict__ dstc,
                             int* __restrict__ ecntc, int* __restrict__ degi,
                             const float* __restrict__ posp, float* __restrict__ m) {
  int n = ecntf ? *ecntf : ecap;
  float vmax = 0.f;
  for (int e = blockIdx.x * blockDim.x + threadIdx.x; e < n;
       e += gridDim.x * blockDim.x) {
    int s2 = nid[srcf[e]], d2 = nid[dstf[e]];
    if (s2 == d2) continue;
    #pragma unroll
    for (int c = 0; c < 3; c++)
      vmax = fmaxf(vmax, fabsf(posp[s2*3+c] - posp[d2*3+c]));
    unsigned key = (unsigned)s2 * (unsigned)Nn + (unsigned)d2;
    unsigned bit = 1u << (key & 31);
    unsigned old = atomicOr(&bitmap[key >> 5], bit);
    if (!(old & bit)) {
      int p = atomicAdd(ecntc, 1);
      srcc[p] = s2; dstc[p] = d2;
      atomicAdd(&degi[d2], 1);
    }
  }
  for (int off = 32; off; off >>= 1) vmax = fmaxf(vmax, __shfl_down(vmax, off, 64));
  __shared__ float red[4];
  int lane = threadIdx.x & 63, wv = threadIdx.x >> 6;
  if (lane == 0) red[wv] = vmax;
  __syncthreads();
  if (threadIdx.x == 0) {
    float mm = fmaxf(fmaxf(red[0], red[1]), fmaxf(red[2], red[3]));
    atomicMax((unsigned*)m, __float_as_uint(mm));
  }
}

// ---------- final pooling + FC ----------
__global__ void k_final_pool(const float* __restrict__ x, const float* __restrict__ pos,
                             const unsigned char* __restrict__ valid,
                             unsigned* __restrict__ xg_ord) {
  long idx = (long)blockIdx.x * blockDim.x + threadIdx.x;
  if (idx >= (long)NL3 * 512) return;
  int v = (int)(idx >> 9), o = (int)(idx & 511);
  if (!valid[v]) return;
  const float vs = 80.f; const int G = 3;
  float p0 = pos[v*3+0], p1 = pos[v*3+1], p2 = pos[v*3+2];
  int c0 = (int)floorf(p0 / vs); c0 = c0 < 0 ? 0 : (c0 > G-1 ? G-1 : c0);
  int c1 = (int)floorf(p1 / vs); c1 = c1 < 0 ? 0 : (c1 > G-1 ? G-1 : c1);
  int c2 = (int)floorf(p2 / vs); c2 = c2 < 0 ? 0 : (c2 > G-1 ? G-1 : c2);
  int cell = (c0 * G + c1) * G + c2;
  int cluster = (v / 125) * 64 + cell;
  atomicMax(&xg_ord[cluster * 512 + o], f2ord(x[idx]));
}

// FC1: only cells 0..26 can be nonzero -> skip 37/64 of the 134MB weight.
// Reads ord-encoded xg directly (ord==0 <=> empty slot -> 0).
__global__ __launch_bounds__(128)
void k_fc1(const unsigned* __restrict__ xg_ord, const float* __restrict__ w,
           float* __restrict__ h) {
  int cellhalf = blockIdx.x >> 3, jb = blockIdx.x & 7;
  int cell = cellhalf >> 1, half = cellhalf & 1;
  int j = jb * 128 + threadIdx.x;
  __shared__ float xs[4][256];
  for (int q = threadIdx.x; q < 1024; q += 128) {
    int b = q >> 8, ci = q & 255;
    unsigned o = xg_ord[((b * 64 + cell) << 9) + half * 256 + ci];
    xs[b][ci] = (o == 0u) ? 0.f : ord2f(o);
  }
  __syncthreads();
  float a0 = 0, a1 = 0, a2 = 0, a3 = 0;
  int cbase = cell * 512 + half * 256;
  for (int ci = 0; ci < 256; ci++) {
    float ww = w[(long)(cbase + ci) * 1024 + j];
    a0 += xs[0][ci] * ww; a1 += xs[1][ci] * ww;
    a2 += xs[2][ci] * ww; a3 += xs[3][ci] * ww;
  }
  atomicAdd(&h[j], a0);        atomicAdd(&h[1024 + j], a1);
  atomicAdd(&h[2048 + j], a2); atomicAdd(&h[3072 + j], a3);
}

__global__ void k_fc1fin(float* __restrict__ h, const float* __restrict__ b) {
  int i = blockIdx.x * blockDim.x + threadIdx.x;
  if (i < 4096) h[i] = eluf(h[i] + b[i & 1023]);
}

__global__ void k_fc2(const float* __restrict__ h, const float* __restrict__ w,
                      const float* __restrict__ b, float* __restrict__ out) {
  int bb = blockIdx.x, t = threadIdx.x;
  float a = 0;
  for (int j = t; j < 1024; j += 256) a += h[bb * 1024 + j] * w[j];
  for (int off = 32; off; off >>= 1) a += __shfl_down(a, off, 64);
  __shared__ float red[4];
  int lane = t & 63, wv = t >> 6;
  if (lane == 0) red[wv] = a;
  __syncthreads();
  if (t == 0) out[bb] = eluf(red[0] + red[1] + red[2] + red[3] + b[0]);
}

// =======================================================================
extern "C" void kernel_launch(void* const* d_in, const int* in_sizes, int n_in,
                              void* d_out, int out_size, void* d_ws, size_t ws_size,
                              hipStream_t stream) {
  const float* x0   = (const float*)d_in[0];
  const float* pos0 = (const float*)d_in[1];
  const int*   ei   = (const int*)d_in[2];
  const float* W1 = (const float*)d_in[4],  *Wr1 = (const float*)d_in[5],  *b1 = (const float*)d_in[6];
  const float* W2 = (const float*)d_in[7],  *Wr2 = (const float*)d_in[8],  *b2 = (const float*)d_in[9];
  const float* W3 = (const float*)d_in[10], *Wr3 = (const float*)d_in[11], *b3 = (const float*)d_in[12];
  const float* W4 = (const float*)d_in[13], *Wr4 = (const float*)d_in[14], *b4 = (const float*)d_in[15];
  const float* fw1 = (const float*)d_in[16], *fb1 = (const float*)d_in[17];
  const float* fw2 = (const float*)d_in[18], *fb2 = (const float*)d_in[19];
  float* out = (float*)d_out;
  const int* src0 = ei;          // edge list in place
  const int* dst0 = ei + E0;

  // ---- workspace layout ----
  char* ws = (char*)d_ws;
  size_t off = 0;
  auto alloc = [&](size_t bytes) -> void* {
    off = (off + 255) & ~(size_t)255;
    void* p = ws + off; off += bytes; return p;
  };
  int* src1 = (int*)alloc(E0 * 4); int* dst1 = (int*)alloc(E0 * 4);
  int* src2 = (int*)alloc(E0 * 4); int* dst2 = (int*)alloc(E0 * 4);
  int* src3 = (int*)alloc(E0 * 4); int* dst3 = (int*)alloc(E0 * 4);
  float* x1  = (float*)alloc((size_t)NL0 * 64 * 4);
  float* x1p = (float*)alloc((size_t)NL1 * 64 * 4);
  float* x2  = (float*)alloc((size_t)NL1 * 128 * 4);
  float* x2p = (float*)alloc((size_t)NL2 * 128 * 4);
  float* x3  = (float*)alloc((size_t)NL2 * 256 * 4);
  float* x3p = (float*)alloc((size_t)NL3 * 256 * 4);
  float* x4  = (float*)alloc((size_t)NL3 * 512 * 4);
  float* pos1 = (float*)alloc(NL1 * 12);
  float* pos2 = (float*)alloc(NL2 * 12);
  float* pos3 = (float*)alloc(NL3 * 12);
  unsigned char* val1 = (unsigned char*)alloc(NL1);
  unsigned char* val2 = (unsigned char*)alloc(NL2);
  unsigned char* val3 = (unsigned char*)alloc(NL3);
  float* ysx = (float*)alloc((size_t)NL1 * 576 * 4);
  float* wc1 = (float*)alloc((size_t)9 * 64 * 4);
  float* wc2 = (float*)alloc((size_t)576 * 128 * 4);
  float* wc3 = (float*)alloc((size_t)1152 * 256 * 4);
  float* wc4 = (float*)alloc((size_t)2304 * 512 * 4);
  float* Cp  = (float*)alloc((size_t)8 * 2048 * 256 * 4 + 256);  // max split-K partials ~16.8MB
  int* nid    = (int*)alloc(NL0 * 4);
  int* rowptr = (int*)alloc((NL0 + 1) * 4);
  int* cursor = (int*)alloc(NL0 * 4);
  int* esrc   = (int*)alloc(E0 * 4);
  float* small = (float*)alloc(256);          // mbuf[4] | ecnt[4]
  float* mbuf = small;
  int* ecnt = (int*)(small + 8);
  // ---- zero region (one memset per pool stage) ----
  char* zstart = (char*)alloc(0);
  float* h      = (float*)alloc(4096 * 4);
  float* cnt    = (float*)alloc(NL1 * 4);
  float* possum = (float*)alloc(NL1 * 12);
  unsigned* pord = (unsigned*)alloc((size_t)NL1 * 64 * 4);  // tail reused as xg_ord
  int* degi     = (int*)alloc(NL0 * 4);
  size_t bmwords = ((size_t)NL1 * NL1 + 31) / 32;
  unsigned* bitmap = (unsigned*)alloc(bmwords * 4);
  char* zend = (char*)alloc(0);
  size_t zbytes = (size_t)(zend - zstart);
  unsigned* xg_ord = pord + (size_t)NL3 * 256;  // zeroed in pool-3 memset, untouched after
  (void)ws_size; (void)in_sizes; (void)n_in; (void)out_size;

  auto cdiv = [](long a, long b) { return (int)((a + b - 1) / b); };

  hipMemsetAsync(small, 0, 256, stream);
  hipMemsetAsync(zstart, 0, zbytes, stream);

  // ===== CSR level 0 =====
  k_deg<<<512, 256, 0, stream>>>(dst0, E0, degi);
  k_absmax<<<512, 256, 0, stream>>>(pos0, src0, dst0, E0, mbuf + 0);
  k_wcat_all<<<1024, 256, 0, stream>>>(W1, Wr1, W2, Wr2, W3, Wr3, W4, Wr4, wc1, wc2, wc3, wc4);
  k_scan<<<1, 1024, 0, stream>>>(degi, rowptr, cursor, NL0);
  k_scatter<<<512, 256, 0, stream>>>(src0, dst0, nullptr, E0, cursor, esrc);

  // ===== Layer 1 (1 -> 64), fused bias+ELU in GEMM =====
  k_gather1<<<cdiv(NL0, 256), 256, 0, stream>>>(pos0, x0, esrc, rowptr, mbuf + 0, ysx, NL0);
  k_gemm<<<dim3(1, cdiv(NL0, 64), 1), 256, 0, stream>>>(ysx, wc1, x1, NL0, 64, 9, 9, 64, 64, 0, b1);

  // ===== Pool 1 (vs=20, G=12, NC=1728) =====
  hipMemsetAsync(zstart, 0, zbytes, stream);
  k_nid<<<cdiv(NL0, 256), 256, 0, stream>>>(pos0, nullptr, NL0, 5000, 20.f, 12, 1728, nid, cnt, possum);
  k_pool_x<<<cdiv((long)NL0 * 64, 256), 256, 0, stream>>>(x1, nullptr, nid, pord, NL0, 64);
  k_pool_fin<<<cdiv((long)NL1 * 64, 256), 256, 0, stream>>>(pord, cnt, possum, x1p, pos1, val1, NL1, 64);
  k_pool_edges<<<512, 256, 0, stream>>>(src0, dst0, nullptr, E0, nid, NL1, bitmap,
                                        src1, dst1, ecnt + 0, degi, pos1, mbuf + 1);
  k_scan<<<1, 1024, 0, stream>>>(degi, rowptr, cursor, NL1);
  k_scatter<<<512, 256, 0, stream>>>(src1, dst1, ecnt + 0, E0, cursor, esrc);

  // ===== Layer 2 (64 -> 128), split-K z=4 =====
  k_gather<<<cdiv(NL1, 4), 256, 0, stream>>>(pos1, x1p, esrc, rowptr, mbuf + 1, ysx, NL1, 64, 1);
  k_gemm<<<dim3(2, cdiv(NL1, 64), 4), 256, 0, stream>>>(ysx, wc2, Cp, NL1, 128, 576, 576, 128, 128, (long)NL1 * 128, nullptr);
  k_reduce<<<cdiv((long)NL1 * 128, 256), 256, 0, stream>>>(Cp, b2, x2, (long)NL1 * 128, 128, 4);

  // ===== Pool 2 (vs=30, G=8, NC=512) =====
  hipMemsetAsync(zstart, 0, zbytes, stream);
  k_nid<<<cdiv(NL1, 256), 256, 0, stream>>>(pos1, val1, NL1, 1728, 30.f, 8, 512, nid, cnt, possum);
  k_pool_x<<<cdiv((long)NL1 * 128, 256), 256, 0, stream>>>(x2, val1, nid, pord, NL1, 128);
  k_pool_fin<<<cdiv((long)NL2 * 128, 256), 256, 0, stream>>>(pord, cnt, possum, x2p, pos2, val2, NL2, 128);
  k_pool_edges<<<512, 256, 0, stream>>>(src1, dst1, ecnt + 0, E0, nid, NL2, bitmap,
                                        src2, dst2, ecnt + 1, degi, pos2, mbuf + 2);
  k_scan<<<1, 1024, 0, stream>>>(degi, rowptr, cursor, NL2);
  k_scatter<<<512, 256, 0, stream>>>(src2, dst2, ecnt + 1, E0, cursor, esrc);

  // ===== Layer 3 (128 -> 256), split-K z=8 =====
  k_gather<<<cdiv(NL2 * 2, 4), 256, 0, stream>>>(pos2, x2p, esrc, rowptr, mbuf + 2, ysx, NL2, 128, 2);
  k_gemm<<<dim3(4, cdiv(NL2, 64), 8), 256, 0, stream>>>(ysx, wc3, Cp, NL2, 256, 1152, 1152, 256, 256, (long)NL2 * 256, nullptr);
  k_reduce<<<cdiv((long)NL2 * 256, 256), 256, 0, stream>>>(Cp, b3, x3, (long)NL2 * 256, 256, 8);

  // ===== Pool 3 (vs=50, G=5, NC=125) =====
  hipMemsetAsync(zstart, 0, zbytes, stream);
  k_nid<<<cdiv(NL2, 256), 256, 0, stream>>>(pos2, val2, NL2, 512, 50.f, 5, 125, nid, cnt, possum);
  k_pool_x<<<cdiv((long)NL2 * 256, 256), 256, 0, stream>>>(x3, val2, nid, pord, NL2, 256);
  k_pool_fin<<<cdiv((long)NL3 * 256, 256), 256, 0, stream>>>(pord, cnt, possum, x3p, pos3, val3, NL3, 256);
  k_pool_edges<<<512, 256, 0, stream>>>(src2, dst2, ecnt + 1, E0, nid, NL3, bitmap,
                                        src3, dst3, ecnt + 2, degi, pos3, mbuf + 3);
  k_scan<<<1, 1024, 0, stream>>>(degi, rowptr, cursor, NL3);
  k_scatter<<<512, 256, 0, stream>>>(src3, dst3, ecnt + 2, E0, cursor, esrc);

  // ===== Layer 4 (256 -> 512), split-K z=16 =====
  k_gather<<<cdiv(NL3 * 4, 4), 256, 0, stream>>>(pos3, x3p, esrc, rowptr, mbuf + 3, ysx, NL3, 256, 4);
  k_gemm<<<dim3(8, cdiv(NL3, 64), 16), 256, 0, stream>>>(ysx, wc4, Cp, NL3, 512, 2304, 2304, 512, 512, (long)NL3 * 512, nullptr);
  k_reduce<<<cdiv((long)NL3 * 512, 256), 256, 0, stream>>>(Cp, b4, x4, (long)NL3 * 512, 512, 16);

  // ===== Final MaxPoolingX (27 cells -> 64 slots) + FC =====
  k_final_pool<<<cdiv((long)NL3 * 512, 256), 256, 0, stream>>>(x4, pos3, val3, xg_ord);
  k_fc1<<<27 * 2 * 8, 128, 0, stream>>>(xg_ord, fw1, h);
  k_fc1fin<<<16, 256, 0, stream>>>(h, fb1);
  k_fc2<<<4, 256, 0, stream>>>(h, fw2, fb2, out);
}

// Round 4
// 482.308 us; speedup vs baseline: 1.7304x; 1.1595x over previous
//
#include <hip/hip_runtime.h>

static constexpr int E0 = 160000;   // level-0 edges
static constexpr int NL0 = 20000;   // nodes level 0
static constexpr int NL1 = 6912;    // 4 * 12^3   (voxel 20)
static constexpr int NL2 = 2048;    // 4 * 8^3    (voxel 30)
static constexpr int NL3 = 500;     // 4 * 5^3    (voxel 50)

typedef short bf16x8 __attribute__((ext_vector_type(8)));
typedef float f32x4 __attribute__((ext_vector_type(4)));

// ---------- helpers ----------
__device__ __forceinline__ unsigned f2ord(float f) {
  unsigned u = __float_as_uint(f);
  return (u & 0x80000000u) ? ~u : (u | 0x80000000u);
}
__device__ __forceinline__ float ord2f(unsigned u) {
  unsigned v = (u & 0x80000000u) ? (u & 0x7fffffffu) : ~u;
  return __uint_as_float(v);
}
__device__ __forceinline__ float eluf(float x) { return x > 0.f ? x : expm1f(x); }
__device__ __forceinline__ void basis8(float u0, float u1, float u2, float* w) {
  float a0 = 1.f - u0, a1 = 1.f - u1, a2 = 1.f - u2;
  w[0] = a0*a1*a2; w[1] = a0*a1*u2; w[2] = a0*u1*a2; w[3] = a0*u1*u2;
  w[4] = u0*a1*a2; w[5] = u0*a1*u2; w[6] = u0*u1*a2; w[7] = u0*u1*u2;
}
__device__ __forceinline__ unsigned short f2b(float f) {  // fp32 -> bf16 RNE
  unsigned u = __float_as_uint(f);
  return (unsigned short)((u + 0x7fffu + ((u >> 16) & 1u)) >> 16);
}
__device__ __forceinline__ float b2f(unsigned short h) {
  return __uint_as_float(((unsigned)h) << 16);
}
__device__ __forceinline__ int clampi(int v, int lo, int hi) {
  return v < lo ? lo : (v > hi ? hi : v);
}

// ---------- fused level-0 degree count + absmax ----------
__global__ void k_deg_absmax(const int* __restrict__ src, const int* __restrict__ dst,
                             const float* __restrict__ pos, int n,
                             int* __restrict__ degi, float* __restrict__ m) {
  float v = 0.f;
  for (int e = blockIdx.x * blockDim.x + threadIdx.x; e < n;
       e += gridDim.x * blockDim.x) {
    int s = src[e], d = dst[e];
    atomicAdd(&degi[d], 1);
    #pragma unroll
    for (int c = 0; c < 3; c++)
      v = fmaxf(v, fabsf(pos[s*3+c] - pos[d*3+c]));
  }
  for (int off = 32; off; off >>= 1) v = fmaxf(v, __shfl_down(v, off, 64));
  __shared__ float red[4];
  int lane = threadIdx.x & 63, wv = threadIdx.x >> 6;
  if (lane == 0) red[wv] = v;
  __syncthreads();
  if (threadIdx.x == 0) {
    float mm = fmaxf(fmaxf(red[0], red[1]), fmaxf(red[2], red[3]));
    atomicMax((unsigned*)m, __float_as_uint(mm));
  }
}

// ---------- weight prep: wc1 fp32; layers 2-4 transposed bf16 hi/lo [N][K] ----------
__global__ __launch_bounds__(256)
void k_wprep(const float* __restrict__ W1, const float* __restrict__ Wr1, float* __restrict__ wc1,
             const float* __restrict__ W2, const float* __restrict__ Wr2,
             const float* __restrict__ W3, const float* __restrict__ Wr3,
             const float* __restrict__ W4, const float* __restrict__ Wr4,
             unsigned short* __restrict__ w2h, unsigned short* __restrict__ w2l,
             unsigned short* __restrict__ w3h, unsigned short* __restrict__ w3l,
             unsigned short* __restrict__ w4h, unsigned short* __restrict__ w4l) {
  __shared__ float T[64][65];
  int b = blockIdx.x;
  const float *W, *Wr; unsigned short *oh, *ol; int K, N, kt, nt;
  if (b < 18)      { W = W2; Wr = Wr2; oh = w2h; ol = w2l; K = 576;  N = 128; kt = b / 2;        nt = b % 2; }
  else if (b < 90) { int q = b - 18; W = W3; Wr = Wr3; oh = w3h; ol = w3l; K = 1152; N = 256; kt = q / 4; nt = q % 4; }
  else             { int q = b - 90; W = W4; Wr = Wr4; oh = w4h; ol = w4l; K = 2304; N = 512; kt = q / 8; nt = q % 8; }
  int k0 = kt * 64, n0 = nt * 64, KW = K - K / 9;   // 8*Ci
  for (int i = threadIdx.x; i < 4096; i += 256) {
    int kk = i >> 6, nn = i & 63; int k = k0 + kk;
    T[kk][nn] = (k < KW) ? W[(long)k * N + n0 + nn] : Wr[(long)(k - KW) * N + n0 + nn];
  }
  __syncthreads();
  for (int i = threadIdx.x; i < 4096; i += 256) {
    int nn = i >> 6, kk = i & 63;
    float v = T[kk][nn];
    unsigned short hu = f2b(v);
    unsigned short lu = f2b(v - b2f(hu));
    long o = (long)(n0 + nn) * K + k0 + kk;
    oh[o] = hu; ol[o] = lu;
  }
  if (b == 0)
    for (int i = threadIdx.x; i < 576; i += 256)
      wc1[i] = (i < 512) ? W1[i] : Wr1[i - 512];
}

// ---------- CSR scan (also clears degi for the next level) ----------
__global__ __launch_bounds__(1024)
void k_scan(int* __restrict__ degi, int* __restrict__ rowptr,
            int* __restrict__ cursor, int N) {
  __shared__ int wsum[16];
  __shared__ int woff[16];
  __shared__ int sbase, stot;
  int lane = threadIdx.x & 63, wv = threadIdx.x >> 6;
  if (threadIdx.x == 0) sbase = 0;
  __syncthreads();
  for (int c0 = 0; c0 < N; c0 += 1024) {
    int i = c0 + threadIdx.x;
    int v = (i < N) ? degi[i] : 0;
    int s = v;
    #pragma unroll
    for (int off = 1; off < 64; off <<= 1) {
      int t = __shfl_up(s, off, 64);
      if (lane >= off) s += t;
    }
    if (lane == 63) wsum[wv] = s;
    __syncthreads();
    if (threadIdx.x < 64) {
      int tv = (lane < 16) ? wsum[lane] : 0;
      int ss = tv;
      #pragma unroll
      for (int off = 1; off < 16; off <<= 1) {
        int t = __shfl_up(ss, off, 64);
        if (lane >= off) ss += t;
      }
      if (lane < 16) woff[lane] = ss - tv;
      if (lane == 15) stot = ss;
    }
    __syncthreads();
    int excl = sbase + woff[wv] + s - v;
    if (i < N) { rowptr[i] = excl; cursor[i] = excl; degi[i] = 0; }
    __syncthreads();
    if (threadIdx.x == 0) sbase += stot;
    __syncthreads();
  }
  if (threadIdx.x == 0) rowptr[N] = sbase;
}

// ---------- scatter into CSR (+ clear dedup bitmap for the next pool) ----------
__global__ void k_scatter(const int* __restrict__ src, const int* __restrict__ dst,
                          const int* __restrict__ ecnt, int ecap,
                          int* __restrict__ cursor, int* __restrict__ esrc,
                          unsigned* __restrict__ bm, long bmw) {
  long gs = (long)gridDim.x * blockDim.x;
  for (long i = (long)blockIdx.x * blockDim.x + threadIdx.x; i < bmw; i += gs) bm[i] = 0u;
  int n = ecnt ? *ecnt : ecap;
  for (int e = blockIdx.x * blockDim.x + threadIdx.x; e < n;
       e += gridDim.x * blockDim.x) {
    int p = atomicAdd(&cursor[dst[e]], 1);
    esrc[p] = src[e];
  }
}

// ---------- fused layer-1: gather + 9x64 matvec + bias + ELU + pool-1 atomics ----------
__global__ __launch_bounds__(256)
void k_l1fused(const float* __restrict__ pos, const float* __restrict__ x0,
               const int* __restrict__ esrc, const int* __restrict__ rowptr,
               const float* __restrict__ m, const float* __restrict__ wc1,
               const float* __restrict__ b1,
               unsigned* __restrict__ pord, float* __restrict__ cnt,
               float* __restrict__ possum, int* __restrict__ nid) {
  int d = blockIdx.x * 4 + (threadIdx.x >> 6);
  int lane = threadIdx.x & 63;
  if (d >= NL0) return;
  float inv = 0.5f / fmaxf(m[0], 1e-9f);
  float pd0 = pos[d*3], pd1 = pos[d*3+1], pd2 = pos[d*3+2];
  int beg = rowptr[d], end = rowptr[d+1];
  float acc[8] = {};
  for (int j = beg; j < end; j++) {
    int s = esrc[j];
    float u0 = (pos[s*3+0] - pd0) * inv + 0.5f;
    float u1 = (pos[s*3+1] - pd1) * inv + 0.5f;
    float u2 = (pos[s*3+2] - pd2) * inv + 0.5f;
    float w[8]; basis8(u0, u1, u2, w);
    float xv = x0[s];
    #pragma unroll
    for (int k = 0; k < 8; k++) acc[k] += w[k] * xv;
  }
  float sc = 1.f / fmaxf((float)(end - beg), 1.f);
  float v = b1[lane] + x0[d] * wc1[512 + lane];
  #pragma unroll
  for (int k = 0; k < 8; k++) v += acc[k] * sc * wc1[k * 64 + lane];
  v = eluf(v);
  // pool 1: vs=20, G=12, NC=1728, div=5000
  int c0 = clampi((int)floorf(pd0 / 20.f), 0, 11);
  int c1 = clampi((int)floorf(pd1 / 20.f), 0, 11);
  int c2 = clampi((int)floorf(pd2 / 20.f), 0, 11);
  int id = (d / 5000) * 1728 + (c0 * 12 + c1) * 12 + c2;
  atomicMax(&pord[(long)id * 64 + lane], f2ord(v));
  if (lane == 0) {
    nid[d] = id;
    atomicAdd(&cnt[id], 1.f);
    atomicAdd(&possum[id*3+0], pd0);
    atomicAdd(&possum[id*3+1], pd1);
    atomicAdd(&possum[id*3+2], pd2);
  }
}

// ---------- gather (levels 2-4): bf16 hi/lo output + zero pool buffers ----------
__global__ __launch_bounds__(256)
void k_gather(const float* __restrict__ pos, const float* __restrict__ x,
              const int* __restrict__ esrc, const int* __restrict__ rowptr,
              const float* __restrict__ m,
              unsigned short* __restrict__ ysh, unsigned short* __restrict__ ysl,
              int N, int Ci, int nchunk,
              unsigned* __restrict__ zptr, long zn) {
  long gs = (long)gridDim.x * blockDim.x;
  for (long i = (long)blockIdx.x * blockDim.x + threadIdx.x; i < zn; i += gs) zptr[i] = 0u;
  int wid = blockIdx.x * 4 + (threadIdx.x >> 6);
  int lane = threadIdx.x & 63;
  int d = wid / nchunk, ch = wid % nchunk;
  if (d >= N) return;
  int co = ch * 64 + lane;
  float inv = 0.5f / fmaxf(m[0], 1e-9f);
  float pd0 = pos[d*3], pd1 = pos[d*3+1], pd2 = pos[d*3+2];
  int beg = rowptr[d], end = rowptr[d+1];
  float acc[8] = {};
  int s_cur = (beg < end) ? esrc[beg] : 0;
  for (int j = beg; j < end; j++) {
    int s = s_cur;
    s_cur = (j + 1 < end) ? esrc[j + 1] : 0;
    float u0 = (pos[s*3+0] - pd0) * inv + 0.5f;
    float u1 = (pos[s*3+1] - pd1) * inv + 0.5f;
    float u2 = (pos[s*3+2] - pd2) * inv + 0.5f;
    float w[8]; basis8(u0, u1, u2, w);
    float xv = x[(long)s * Ci + co];
    #pragma unroll
    for (int k = 0; k < 8; k++) acc[k] += w[k] * xv;
  }
  float sc = 1.f / fmaxf((float)(end - beg), 1.f);
  long row = (long)d * 9 * Ci;
  #pragma unroll
  for (int k = 0; k < 8; k++) {
    float v = acc[k] * sc;
    unsigned short hu = f2b(v);
    ysh[row + k * Ci + co] = hu;
    ysl[row + k * Ci + co] = f2b(v - b2f(hu));
  }
  float xd = x[(long)d * Ci + co];
  unsigned short hu = f2b(xd);
  ysh[row + 8 * Ci + co] = hu;
  ysl[row + 8 * Ci + co] = f2b(xd - b2f(hu));
}

// ---------- MFMA bf16 3-pass GEMM: C[z] = A @ B^T-stored, split-K ----------
__global__ __launch_bounds__(256)
void k_gemm_mfma(const unsigned short* __restrict__ Ah, const unsigned short* __restrict__ Al,
                 const unsigned short* __restrict__ Bh, const unsigned short* __restrict__ Bl,
                 float* __restrict__ Cp, int M, int N, int K, int ksl, long zstride) {
  __shared__ unsigned short Ash[64][40], Asl[64][40], Bsh[64][40], Bsl[64][40];
  int m0 = blockIdx.y * 64, n0 = blockIdx.x * 64;
  int kbeg = blockIdx.z * ksl;
  int t = threadIdx.x, w = t >> 6, lane = t & 63;
  int r = t >> 2, sg = (t & 3) * 8;
  f32x4 acc[4] = {};
  for (int kt = 0; kt < ksl; kt += 32) {
    bf16x8 va = {}, vb = {};
    if (m0 + r < M) {
      long ga = (long)(m0 + r) * K + kbeg + kt + sg;
      va = *(const bf16x8*)&Ah[ga];
      vb = *(const bf16x8*)&Al[ga];
    }
    *(bf16x8*)&Ash[r][sg] = va;
    *(bf16x8*)&Asl[r][sg] = vb;
    long gb = (long)(n0 + r) * K + kbeg + kt + sg;
    *(bf16x8*)&Bsh[r][sg] = *(const bf16x8*)&Bh[gb];
    *(bf16x8*)&Bsl[r][sg] = *(const bf16x8*)&Bl[gb];
    __syncthreads();
    int ar = (w << 4) + (lane & 15), kq = (lane >> 4) << 3;
    bf16x8 ah = *(const bf16x8*)&Ash[ar][kq];
    bf16x8 al = *(const bf16x8*)&Asl[ar][kq];
    #pragma unroll
    for (int nt = 0; nt < 4; nt++) {
      int br = (nt << 4) + (lane & 15);
      bf16x8 bh = *(const bf16x8*)&Bsh[br][kq];
      bf16x8 bl = *(const bf16x8*)&Bsl[br][kq];
      acc[nt] = __builtin_amdgcn_mfma_f32_16x16x32_bf16(al, bh, acc[nt], 0, 0, 0);
      acc[nt] = __builtin_amdgcn_mfma_f32_16x16x32_bf16(ah, bl, acc[nt], 0, 0, 0);
      acc[nt] = __builtin_amdgcn_mfma_f32_16x16x32_bf16(ah, bh, acc[nt], 0, 0, 0);
    }
    __syncthreads();
  }
  float* Co = Cp + zstride * blockIdx.z;
  int row0 = m0 + (w << 4) + ((lane >> 4) << 2);
  int col = n0 + (lane & 15);
  #pragma unroll
  for (int nt = 0; nt < 4; nt++)
    #pragma unroll
    for (int q = 0; q < 4; q++) {
      int gm = row0 + q;
      if (gm < M) Co[(long)gm * N + col + nt * 16] = acc[nt][q];
    }
}

// ---------- split-K reduce + bias + ELU + voxel pool (or final MaxPoolingX) ----------
__global__ void k_reduce_pool(const float* __restrict__ Cp, const float* __restrict__ bias,
                              long MN, int Co, int z,
                              const float* __restrict__ pos, const unsigned char* __restrict__ valid,
                              int div, float vs, int G, int SLOT,
                              unsigned* __restrict__ pord, float* __restrict__ cnt,
                              float* __restrict__ possum, int* __restrict__ nid) {
  long idx = (long)blockIdx.x * blockDim.x + threadIdx.x;
  if (idx >= MN) return;
  int n = (int)(idx / Co), o = (int)(idx % Co);
  float s = 0.f;
  for (int q = 0; q < z; q++) s += Cp[q * MN + idx];
  float v = eluf(s + bias[o]);
  float p0 = pos[n*3], p1 = pos[n*3+1], p2 = pos[n*3+2];
  int c0 = clampi((int)floorf(p0 / vs), 0, G - 1);
  int c1 = clampi((int)floorf(p1 / vs), 0, G - 1);
  int c2 = clampi((int)floorf(p2 / vs), 0, G - 1);
  int id = (n / div) * SLOT + (c0 * G + c1) * G + c2;
  if (o == 0 && nid) nid[n] = id;
  if (!valid[n]) return;
  atomicMax(&pord[(long)id * Co + o], f2ord(v));
  if (o == 0 && cnt) {
    atomicAdd(&cnt[id], 1.f);
    atomicAdd(&possum[id*3+0], p0);
    atomicAdd(&possum[id*3+1], p1);
    atomicAdd(&possum[id*3+2], p2);
  }
}

// ---------- pool finalize: pord/cnt/possum -> xp, posp, validp ----------
__global__ void k_pool_fin(const unsigned* __restrict__ pord, const float* __restrict__ cnt,
                           const float* __restrict__ possum, float* __restrict__ xp,
                           float* __restrict__ posp, unsigned char* __restrict__ validp,
                           int Nn, int Cf) {
  long idx = (long)blockIdx.x * blockDim.x + threadIdx.x;
  if (idx >= (long)Nn * Cf) return;
  int n = (int)(idx / Cf), o = (int)(idx % Cf);
  float c = cnt[n];
  xp[idx] = (c > 0.f) ? ord2f(pord[idx]) : 0.f;
  if (o == 0) {
    validp[n] = (c > 0.f) ? 1 : 0;
    float ic = 1.f / fmaxf(c, 1.f);
    posp[n*3+0] = possum[n*3+0] * ic;
    posp[n*3+1] = possum[n*3+1] * ic;
    posp[n*3+2] = possum[n*3+2] * ic;
  }
}

// ---------- edge coarsening: dedup + compaction + next deg + next absmax ----------
__global__ void k_pool_edges(const int* __restrict__ srcf, const int* __restrict__ dstf,
                             const int* __restrict__ ecntf, int ecap,
                             const int* __restrict__ nid, int Nn,
                             unsigned* __restrict__ bitmap,
                             int* __restrict__ srcc, int* __restrict__ dstc,
                             int* __restrict__ ecntc, int* __restrict__ degi,
                             const float* __restrict__ posp, float* __restrict__ m) {
  int n = ecntf ? *ecntf : ecap;
  float vmax = 0.f;
  for (int e = blockIdx.x * blockDim.x + threadIdx.x; e < n;
       e += gridDim.x * blockDim.x) {
    int s2 = nid[srcf[e]], d2 = nid[dstf[e]];
    if (s2 == d2) continue;
    #pragma unroll
    for (int c = 0; c < 3; c++)
      vmax = fmaxf(vmax, fabsf(posp[s2*3+c] - posp[d2*3+c]));
    unsigned key = (unsigned)s2 * (unsigned)Nn + (unsigned)d2;
    unsigned bit = 1u << (key & 31);
    unsigned old = atomicOr(&bitmap[key >> 5], bit);
    if (!(old & bit)) {
      int p = atomicAdd(ecntc, 1);
      srcc[p] = s2; dstc[p] = d2;
      atomicAdd(&degi[d2], 1);
    }
  }
  for (int off = 32; off; off >>= 1) vmax = fmaxf(vmax, __shfl_down(vmax, off, 64));
  __shared__ float red[4];
  int lane = threadIdx.x & 63, wv = threadIdx.x >> 6;
  if (lane == 0) red[wv] = vmax;
  __syncthreads();
  if (threadIdx.x == 0) {
    float mm = fmaxf(fmaxf(red[0], red[1]), fmaxf(red[2], red[3]));
    atomicMax((unsigned*)m, __float_as_uint(mm));
  }
}

// ---------- FC1 (skips the 37/64 always-empty cells) ----------
__global__ __launch_bounds__(128)
void k_fc1(const unsigned* __restrict__ xg_ord, const float* __restrict__ w,
           float* __restrict__ h) {
  int cellhalf = blockIdx.x >> 3, jb = blockIdx.x & 7;
  int cell = cellhalf >> 1, half = cellhalf & 1;
  int j = jb * 128 + threadIdx.x;
  __shared__ float xs[4][256];
  for (int q = threadIdx.x; q < 1024; q += 128) {
    int b = q >> 8, ci = q & 255;
    unsigned o = xg_ord[((b * 64 + cell) << 9) + half * 256 + ci];
    xs[b][ci] = (o == 0u) ? 0.f : ord2f(o);
  }
  __syncthreads();
  float a0 = 0, a1 = 0, a2 = 0, a3 = 0;
  int cbase = cell * 512 + half * 256;
  for (int ci = 0; ci < 256; ci++) {
    float ww = w[(long)(cbase + ci) * 1024 + j];
    a0 += xs[0][ci] * ww; a1 += xs[1][ci] * ww;
    a2 += xs[2][ci] * ww; a3 += xs[3][ci] * ww;
  }
  atomicAdd(&h[j], a0);        atomicAdd(&h[1024 + j], a1);
  atomicAdd(&h[2048 + j], a2); atomicAdd(&h[3072 + j], a3);
}

// ---------- FC2 (fc1 bias+ELU fused) ----------
__global__ void k_fc2(const float* __restrict__ h, const float* __restrict__ fb1,
                      const float* __restrict__ w, const float* __restrict__ b,
                      float* __restrict__ out) {
  int bb = blockIdx.x, t = threadIdx.x;
  float a = 0;
  for (int j = t; j < 1024; j += 256) a += eluf(h[bb * 1024 + j] + fb1[j]) * w[j];
  for (int off = 32; off; off >>= 1) a += __shfl_down(a, off, 64);
  __shared__ float red[4];
  int lane = t & 63, wv = t >> 6;
  if (lane == 0) red[wv] = a;
  __syncthreads();
  if (t == 0) out[bb] = eluf(red[0] + red[1] + red[2] + red[3] + b[0]);
}

// =======================================================================
extern "C" void kernel_launch(void* const* d_in, const int* in_sizes, int n_in,
                              void* d_out, int out_size, void* d_ws, size_t ws_size,
                              hipStream_t stream) {
  const float* x0   = (const float*)d_in[0];
  const float* pos0 = (const float*)d_in[1];
  const int*   ei   = (const int*)d_in[2];
  const float* W1 = (const float*)d_in[4],  *Wr1 = (const float*)d_in[5],  *b1 = (const float*)d_in[6];
  const float* W2 = (const float*)d_in[7],  *Wr2 = (const float*)d_in[8],  *b2 = (const float*)d_in[9];
  const float* W3 = (const float*)d_in[10], *Wr3 = (const float*)d_in[11], *b3 = (const float*)d_in[12];
  const float* W4 = (const float*)d_in[13], *Wr4 = (const float*)d_in[14], *b4 = (const float*)d_in[15];
  const float* fw1 = (const float*)d_in[16], *fb1 = (const float*)d_in[17];
  const float* fw2 = (const float*)d_in[18], *fb2 = (const float*)d_in[19];
  float* out = (float*)d_out;
  const int* src0 = ei;
  const int* dst0 = ei + E0;

  // ---- workspace ----
  char* ws = (char*)d_ws;
  size_t off = 0;
  auto alloc = [&](size_t bytes) -> void* {
    off = (off + 255) & ~(size_t)255;
    void* p = ws + off; off += bytes; return p;
  };
  int* src1 = (int*)alloc(E0 * 4); int* dst1 = (int*)alloc(E0 * 4);
  int* src2 = (int*)alloc(E0 * 4); int* dst2 = (int*)alloc(E0 * 4);
  int* src3 = (int*)alloc(E0 * 4); int* dst3 = (int*)alloc(E0 * 4);
  float* x1p = (float*)alloc((size_t)NL1 * 64 * 4);
  float* x2p = (float*)alloc((size_t)NL2 * 128 * 4);
  float* x3p = (float*)alloc((size_t)NL3 * 256 * 4);
  float* pos1 = (float*)alloc(NL1 * 12);
  float* pos2 = (float*)alloc(NL2 * 12);
  float* pos3 = (float*)alloc(NL3 * 12);
  unsigned char* val1 = (unsigned char*)alloc(NL1);
  unsigned char* val2 = (unsigned char*)alloc(NL2);
  unsigned char* val3 = (unsigned char*)alloc(NL3);
  unsigned short* ysh = (unsigned short*)alloc((size_t)NL1 * 576 * 2);
  unsigned short* ysl = (unsigned short*)alloc((size_t)NL1 * 576 * 2);
  float* wc1 = (float*)alloc(576 * 4);
  unsigned short* w2h = (unsigned short*)alloc((size_t)576 * 128 * 2);
  unsigned short* w2l = (unsigned short*)alloc((size_t)576 * 128 * 2);
  unsigned short* w3h = (unsigned short*)alloc((size_t)1152 * 256 * 2);
  unsigned short* w3l = (unsigned short*)alloc((size_t)1152 * 256 * 2);
  unsigned short* w4h = (unsigned short*)alloc((size_t)2304 * 512 * 2);
  unsigned short* w4l = (unsigned short*)alloc((size_t)2304 * 512 * 2);
  float* Cp  = (float*)alloc((size_t)6 * 2048 * 256 * 4);   // max split-K partials (12.6MB)
  int* nid    = (int*)alloc(NL0 * 4);
  int* rowptr = (int*)alloc((NL0 + 1) * 4);
  int* cursor = (int*)alloc(NL0 * 4);
  int* esrc   = (int*)alloc(E0 * 4);
  // ---- zero region: [zA: h|cnt|possum|pord]  [zB: degi|bitmap|small] ----
  char* zA = (char*)alloc(0);
  float* h      = (float*)alloc(4096 * 4);
  float* cnt    = (float*)alloc(NL1 * 4);
  float* possum = (float*)alloc(NL1 * 12);
  unsigned* pord = (unsigned*)alloc((size_t)NL1 * 64 * 4);
  char* zAend = (char*)alloc(0);
  int* degi = (int*)alloc(NL0 * 4);
  size_t bmwords = ((size_t)NL1 * NL1 + 31) / 32;
  unsigned* bitmap = (unsigned*)alloc(bmwords * 4);
  float* mbuf = (float*)alloc(64);
  int* ecnt = (int*)(mbuf + 8);
  char* zend = (char*)alloc(0);
  long zAn = (long)(zAend - zA) / 4;                 // words in zA
  size_t zbytes = (size_t)(zend - zA);
  unsigned* xg_ord = pord + (size_t)NL3 * 256;       // final 4*64*512 slots in pord tail
  (void)ws_size; (void)in_sizes; (void)n_in; (void)out_size;

  auto cdiv = [](long a, long b) { return (int)((a + b - 1) / b); };

  // one upfront clear of all accumulator state
  hipMemsetAsync(zA, 0, zbytes, stream);

  // ===== level-0 CSR + prep =====
  k_deg_absmax<<<512, 256, 0, stream>>>(src0, dst0, pos0, E0, degi, mbuf + 0);
  k_wprep<<<378, 256, 0, stream>>>(W1, Wr1, wc1, W2, Wr2, W3, Wr3, W4, Wr4,
                                   w2h, w2l, w3h, w3l, w4h, w4l);
  k_scan<<<1, 1024, 0, stream>>>(degi, rowptr, cursor, NL0);
  k_scatter<<<512, 256, 0, stream>>>(src0, dst0, nullptr, E0, cursor, esrc, bitmap, bmwords);

  // ===== layer 1 (fused conv + pool-1 atomics) =====
  k_l1fused<<<5000, 256, 0, stream>>>(pos0, x0, esrc, rowptr, mbuf + 0, wc1, b1,
                                      pord, cnt, possum, nid);
  k_pool_fin<<<cdiv((long)NL1 * 64, 256), 256, 0, stream>>>(pord, cnt, possum, x1p, pos1, val1, NL1, 64);
  k_pool_edges<<<512, 256, 0, stream>>>(src0, dst0, nullptr, E0, nid, NL1, bitmap,
                                        src1, dst1, ecnt + 0, degi, pos1, mbuf + 1);
  k_scan<<<1, 1024, 0, stream>>>(degi, rowptr, cursor, NL1);
  k_scatter<<<512, 256, 0, stream>>>(src1, dst1, ecnt + 0, E0, cursor, esrc, bitmap, bmwords);

  // ===== layer 2 (64 -> 128), K=576, z=3 =====
  k_gather<<<cdiv(NL1, 4), 256, 0, stream>>>(pos1, x1p, esrc, rowptr, mbuf + 1,
                                             ysh, ysl, NL1, 64, 1, (unsigned*)zA, zAn);
  k_gemm_mfma<<<dim3(2, cdiv(NL1, 64), 3), 256, 0, stream>>>(ysh, ysl, w2h, w2l, Cp,
                                                             NL1, 128, 576, 192, (long)NL1 * 128);
  k_reduce_pool<<<cdiv((long)NL1 * 128, 256), 256, 0, stream>>>(
      Cp, b2, (long)NL1 * 128, 128, 3, pos1, val1, 1728, 30.f, 8, 512, pord, cnt, possum, nid);
  k_pool_fin<<<cdiv((long)NL2 * 128, 256), 256, 0, stream>>>(pord, cnt, possum, x2p, pos2, val2, NL2, 128);
  k_pool_edges<<<512, 256, 0, stream>>>(src1, dst1, ecnt + 0, E0, nid, NL2, bitmap,
                                        src2, dst2, ecnt + 1, degi, pos2, mbuf + 2);
  k_scan<<<1, 1024, 0, stream>>>(degi, rowptr, cursor, NL2);
  k_scatter<<<512, 256, 0, stream>>>(src2, dst2, ecnt + 1, E0, cursor, esrc, bitmap, bmwords);

  // ===== layer 3 (128 -> 256), K=1152, z=6 =====
  k_gather<<<cdiv(NL2 * 2, 4), 256, 0, stream>>>(pos2, x2p, esrc, rowptr, mbuf + 2,
                                                 ysh, ysl, NL2, 128, 2, (unsigned*)zA, zAn);
  k_gemm_mfma<<<dim3(4, cdiv(NL2, 64), 6), 256, 0, stream>>>(ysh, ysl, w3h, w3l, Cp,
                                                             NL2, 256, 1152, 192, (long)NL2 * 256);
  k_reduce_pool<<<cdiv((long)NL2 * 256, 256), 256, 0, stream>>>(
      Cp, b3, (long)NL2 * 256, 256, 6, pos2, val2, 512, 50.f, 5, 125, pord, cnt, possum, nid);
  k_pool_fin<<<cdiv((long)NL3 * 256, 256), 256, 0, stream>>>(pord, cnt, possum, x3p, pos3, val3, NL3, 256);
  k_pool_edges<<<512, 256, 0, stream>>>(src2, dst2, ecnt + 1, E0, nid, NL3, bitmap,
                                        src3, dst3, ecnt + 2, degi, pos3, mbuf + 3);
  k_scan<<<1, 1024, 0, stream>>>(degi, rowptr, cursor, NL3);
  k_scatter<<<512, 256, 0, stream>>>(src3, dst3, ecnt + 2, E0, cursor, esrc, bitmap, bmwords);

  // ===== layer 4 (256 -> 512), K=2304, z=12; final MaxPoolingX fused =====
  k_gather<<<cdiv(NL3 * 4, 4), 256, 0, stream>>>(pos3, x3p, esrc, rowptr, mbuf + 3,
                                                 ysh, ysl, NL3, 256, 4, (unsigned*)zA, zAn);
  k_gemm_mfma<<<dim3(8, cdiv(NL3, 64), 12), 256, 0, stream>>>(ysh, ysl, w4h, w4l, Cp,
                                                              NL3, 512, 2304, 192, (long)NL3 * 512);
  k_reduce_pool<<<cdiv((long)NL3 * 512, 256), 256, 0, stream>>>(
      Cp, b4, (long)NL3 * 512, 512, 12, pos3, val3, 125, 80.f, 3, 64, xg_ord, nullptr, nullptr, nullptr);

  // ===== FC =====
  k_fc1<<<27 * 2 * 8, 128, 0, stream>>>(xg_ord, fw1, h);
  k_fc2<<<4, 256, 0, stream>>>(h, fb1, fw2, fb2, out);
}